// Round 3
// baseline (2046.658 us; speedup 1.0000x reference)
//
#include <hip/hip_runtime.h>
#include <stdint.h>

#define GG 64
#define NN 256
#define FF 20
#define HH 32
#define KK 5
#define NS 100

// out offsets (floats)
#define O_PT   0
#define O_LA   20971520
#define O_ZMU  20971840
#define O_LOSS 21496128

// ws offsets (floats/ints)
#define W_HA   0
#define W_LT   524288          /* [K][G][N][N] int mantissa-threshold */
#define W_PART 21495808        /* [NS*G] */

typedef __attribute__((ext_vector_type(8))) short short8v;
typedef __attribute__((ext_vector_type(4))) short short4v;
typedef __attribute__((ext_vector_type(4))) float float4v;

__device__ __forceinline__ uint32_t rotl32(uint32_t v, int n){ return (v << n) | (v >> (32 - n)); }

// JAX threefry2x32 (20 rounds), key (k0,k1), counter (x0,x1)
__device__ __forceinline__ void tf2x32(uint32_t k0, uint32_t k1, uint32_t x0, uint32_t x1,
                                       uint32_t& o0, uint32_t& o1){
  uint32_t k2 = k0 ^ k1 ^ 0x1BD11BDAu;
  x0 += k0; x1 += k1;
  x0 += x1; x1 = rotl32(x1,13); x1 ^= x0;
  x0 += x1; x1 = rotl32(x1,15); x1 ^= x0;
  x0 += x1; x1 = rotl32(x1,26); x1 ^= x0;
  x0 += x1; x1 = rotl32(x1, 6); x1 ^= x0;
  x0 += k1; x1 += k2 + 1u;
  x0 += x1; x1 = rotl32(x1,17); x1 ^= x0;
  x0 += x1; x1 = rotl32(x1,29); x1 ^= x0;
  x0 += x1; x1 = rotl32(x1,16); x1 ^= x0;
  x0 += x1; x1 = rotl32(x1,24); x1 ^= x0;
  x0 += k2; x1 += k0 + 2u;
  x0 += x1; x1 = rotl32(x1,13); x1 ^= x0;
  x0 += x1; x1 = rotl32(x1,15); x1 ^= x0;
  x0 += x1; x1 = rotl32(x1,26); x1 ^= x0;
  x0 += x1; x1 = rotl32(x1, 6); x1 ^= x0;
  x0 += k0; x1 += k1 + 3u;
  x0 += x1; x1 = rotl32(x1,17); x1 ^= x0;
  x0 += x1; x1 = rotl32(x1,29); x1 ^= x0;
  x0 += x1; x1 = rotl32(x1,16); x1 ^= x0;
  x0 += x1; x1 = rotl32(x1,24); x1 ^= x0;
  x0 += k1; x1 += k2 + 4u;
  x0 += x1; x1 = rotl32(x1,13); x1 ^= x0;
  x0 += x1; x1 = rotl32(x1,15); x1 ^= x0;
  x0 += x1; x1 = rotl32(x1,26); x1 ^= x0;
  x0 += x1; x1 = rotl32(x1, 6); x1 ^= x0;
  o0 = x0 + k2; o1 = x1 + k0 + 5u;
}

__device__ __forceinline__ float u01(uint32_t b){
  return __uint_as_float((b >> 9) | 0x3f800000u) - 1.0f;
}

__device__ __forceinline__ unsigned short f2bf(float f){
  uint32_t u = __float_as_uint(f);
  uint32_t r = u + 0x7FFFu + ((u >> 16) & 1u);
  return (unsigned short)(r >> 16);
}

// XLA ErfInv32 (Giles 2012)
__device__ __forceinline__ float erfinv_f(float x){
  float w = -log1pf(-x*x);
  float p;
  if (w < 5.f){
    w = w - 2.5f;
    p = 2.81022636e-08f;
    p = fmaf(p,w, 3.43273939e-07f);
    p = fmaf(p,w,-3.5233877e-06f);
    p = fmaf(p,w,-4.39150654e-06f);
    p = fmaf(p,w, 0.00021858087f);
    p = fmaf(p,w,-0.00125372503f);
    p = fmaf(p,w,-0.00417768164f);
    p = fmaf(p,w, 0.246640727f);
    p = fmaf(p,w, 1.50140941f);
  } else {
    w = sqrtf(w) - 3.f;
    p = -0.000200214257f;
    p = fmaf(p,w, 0.000100950558f);
    p = fmaf(p,w, 0.00134934322f);
    p = fmaf(p,w,-0.00367342844f);
    p = fmaf(p,w, 0.00573950773f);
    p = fmaf(p,w,-0.0076224613f);
    p = fmaf(p,w, 0.00943887047f);
    p = fmaf(p,w, 1.00167406f);
    p = fmaf(p,w, 2.83297682f);
  }
  return p*x;
}

// ---------- K1: per-node encoders: Z_mu -> out, ha -> ws ----------
__global__ void k_encode(const float* __restrict__ X,
                         const float* __restrict__ Wz1, const float* __restrict__ bz1,
                         const float* __restrict__ Wz2, const float* __restrict__ bz2,
                         const float* __restrict__ Wa1, const float* __restrict__ ba1,
                         float* __restrict__ out, float* __restrict__ ws){
  int g = blockIdx.y, nt = blockIdx.x;   // nt 0..31 (8 nodes each)
  int tid = threadIdx.x;
  int nl = tid >> 5, h = tid & 31;
  __shared__ float xrow[8][FF];
  __shared__ float hzrow[8][HH];
  if (tid < 8*FF){
    int a = tid / FF, b = tid % FF;
    xrow[a][b] = X[(g*NN + nt*8 + a)*FF + b];
  }
  __syncthreads();
  float hz = bz1[h], ha = ba1[h];
  for (int f = 0; f < FF; ++f){
    float xv = xrow[nl][f];
    hz = fmaf(xv, Wz1[f*HH + h], hz);
    ha = fmaf(xv, Wa1[f*HH + h], ha);
  }
  hz = fmaxf(hz, 0.f); ha = fmaxf(ha, 0.f);
  hzrow[nl][h] = hz;
  int n = nt*8 + nl;
  ws[W_HA + (g*NN + n)*HH + h] = ha;
  __syncthreads();
  float zm = bz2[h];
  for (int hh = 0; hh < HH; ++hh)
    zm = fmaf(hzrow[nl][hh], Wz2[hh*HH + h], zm);
  out[O_ZMU + (g*NN + n)*HH + h] = zm;
}

// ---------- K2: logit_alpha = mean_n(ha) @ Walpha + balpha ----------
__global__ void k_alpha(const float* __restrict__ Walpha, const float* __restrict__ balpha,
                        float* __restrict__ out, const float* __restrict__ ws){
  int g = blockIdx.x; int tid = threadIdx.x;
  int h = tid & 31, p = tid >> 5;  // p 0..7
  __shared__ float sums[8][HH];
  __shared__ float meanh[HH];
  float s = 0.f;
  for (int n = p; n < NN; n += 8) s += ws[W_HA + (g*NN + n)*HH + h];
  sums[p][h] = s;
  __syncthreads();
  if (p == 0){
    float t = 0.f;
    for (int q = 0; q < 8; ++q) t += sums[q][h];
    meanh[h] = t * (1.0f/256.0f);
  }
  __syncthreads();
  if (tid < KK){
    float la = balpha[tid];
    for (int hh = 0; hh < HH; ++hh) la = fmaf(meanh[hh], Walpha[hh*KK + tid], la);
    out[O_LA + g*KK + tid] = la;
  }
}

// ---------- K3: prob_theta (out) + int mantissa threshold (ws, k-major) ----------
// edge set iff (bits>>9) > tint, where tint encodes u > sigmoid(-logit)
__global__ void k_theta(const float* __restrict__ Wtheta,
                        float* __restrict__ out, float* __restrict__ ws){
  int jt = blockIdx.x, it = blockIdx.y, g = blockIdx.z;
  int tid = threadIdx.x;
  __shared__ float wth[HH*HH*KK];     // [h][f*K+k]
  __shared__ float hai[16][HH], haj[16][HH];
  __shared__ float tloc[16][HH*KK];   // [i][f*K+k]
  for (int idx = tid; idx < HH*HH*KK; idx += 256) wth[idx] = Wtheta[idx];
  for (int idx = tid; idx < 16*HH; idx += 256){
    int r = idx >> 5, c = idx & 31;
    hai[r][c] = ws[W_HA + (g*NN + it*16 + r)*HH + c];
    haj[r][c] = ws[W_HA + (g*NN + jt*16 + r)*HH + c];
  }
  __syncthreads();
  for (int idx = tid; idx < 16*HH*KK; idx += 256){
    int i = idx / (HH*KK), rem = idx % (HH*KK);
    float a = 0.f;
    for (int hh = 0; hh < HH; ++hh) a = fmaf(hai[i][hh], wth[hh*(HH*KK) + rem], a);
    tloc[i][rem] = a;
  }
  __syncthreads();
  int il = tid >> 4, jl = tid & 15;
  float acc[KK] = {0,0,0,0,0};
  for (int f = 0; f < HH; ++f){
    float hv = haj[jl][f];
    #pragma unroll
    for (int k = 0; k < KK; ++k) acc[k] = fmaf(tloc[il][f*KK+k], hv, acc[k]);
  }
  int i = it*16 + il, j = jt*16 + jl;
  int* tint = (int*)ws;
  #pragma unroll
  for (int k = 0; k < KK; ++k){
    float v = acc[k];
    float s = 1.f / (1.f + expf(-v));
    float thrf = 1.f - s;                            // sigmoid(-v)
    float fthr = (thrf - 1e-6f) * (1.f / (1.f - 2e-6f));
    int t;
    if (fthr <= 0.f) t = -1;
    else if (fthr >= 1.f) t = 0x7FFFFFFF;
    else t = (int)(__float_as_uint(1.0f + fthr) - 0x3f800000u);
    tint[W_LT + ((size_t)k*GG + g)*NN*NN + i*NN + j] = t;
    out[O_PT + ((size_t)(g*NN + i)*NN + j)*KK + k] = (i == j) ? 0.f : s;
  }
}

// ---------- K4: the whole MC loop, one block per (it, g) ----------
__global__ __launch_bounds__(512, 6)
void k_loop(const float* __restrict__ Wd1, const float* __restrict__ bd1,
            const float* __restrict__ Wd2, const float* __restrict__ bd2,
            const float* __restrict__ X, const int* __restrict__ seedp,
            const float* __restrict__ outro, float* __restrict__ ws){
  int g  = blockIdx.x;   // 0..63
  int it = blockIdx.y;   // 0..99
  int tid = threadIdx.x; // 0..511
  int lane = tid & 63, wvid = tid >> 6;
  int l15 = lane & 15, l4 = lane >> 4;

  __shared__ unsigned short zT[HH][264];   // bf16 Z^T then h^T        16.9KB
  __shared__ unsigned short azb[NN][40];   // bf16 AZ then Ah, 80B rows 20.5KB
  __shared__ uint32_t Abits[NN*9];         // adjacency bits, 9 w/row   9.2KB
  __shared__ unsigned short wd1T[HH*40];   // Wd1^T bf16 [m][k]         2.5KB
  __shared__ unsigned short wd2T[HH*40];   // Wd2^T bf16 padded [f][k]  2.5KB
  __shared__ float bd1s[HH], bd2p[HH];
  __shared__ uint32_t skey[6];
  __shared__ int skmax;

  if (tid == 0){
    uint32_t seed = (uint32_t)(*seedp);
    uint32_t b0, b1, a0, a1, c0, c1, d0, d1;
    tf2x32(0u, seed, 0u, (uint32_t)it, b0, b1);  // fold_in(base, it)
    tf2x32(b0, b1, 0u, 0u, a0, a1);              // split -> k1
    tf2x32(b0, b1, 0u, 1u, c0, c1);              // k2
    tf2x32(b0, b1, 0u, 2u, d0, d1);              // k3
    skey[0]=a0; skey[1]=a1; skey[2]=c0; skey[3]=c1; skey[4]=d0; skey[5]=d1;
    // gumbel-softmax hard component selection
    float best = -3.4e38f; int arg = 0;
    for (int k = 0; k < KK; ++k){
      uint32_t e = (uint32_t)(g*KK + k), r0, r1;
      tf2x32(c0, c1, 0u, e, r0, r1);
      float f = u01(r0 ^ r1);
      float u = fmaxf(1.17549435e-38f, f + 1.17549435e-38f);
      float gum = -logf(-logf(u));
      float z = outro[O_LA + g*KK + k] + gum;
      if (z > best){ best = z; arg = k; }
    }
    skmax = arg;
  }
  for (int idx = tid; idx < HH*HH; idx += 512){
    int k = idx >> 5, m = idx & 31;
    wd1T[m*40 + k] = f2bf(Wd1[idx]);
    int f = m;
    wd2T[f*40 + k] = (f < FF) ? f2bf(Wd2[k*FF + f]) : 0;
  }
  if (tid < HH) bd1s[tid] = bd1[tid];
  if (tid < HH) bd2p[tid] = (tid < FF) ? bd2[tid] : 0.f;
  for (int idx = tid; idx < NN*9; idx += 512) Abits[idx] = 0u;
  __syncthreads();

  // ---- phase 1: sample_Z = Z_mu + std*normal -> zT (bf16, transposed) ----
  #pragma unroll
  for (int kk = 0; kk < 4; ++kk){
    int n = kk*64 + lane;
    #pragma unroll
    for (int hh = 0; hh < 4; ++hh){
      int h = wvid*4 + hh;
      uint32_t e = (uint32_t)(g*NN*HH + n*HH + h), r0, r1;
      tf2x32(skey[0], skey[1], 0u, e, r0, r1);
      float f = u01(r0 ^ r1);
      float u = fmaf(f, 2.0f, -0.99999994f);
      float nrm = 1.41421356f * erfinv_f(u);
      float zf = outro[O_ZMU + g*NN*HH + n*HH + h] + 0.22313016f * nrm;
      zT[h][n] = f2bf(zf);
    }
  }

  // ---- phase 2a: ballot-built strict-lower adjacency rows ----
  {
    const int* tintp = (const int*)ws + W_LT + ((size_t)skmax*GG + g)*NN*NN;
    for (int i = wvid; i < NN; i += 8){
      for (int jw = 0; jw*64 < i; ++jw){
        int j0 = jw*64 + lane;
        int t = tintp[i*NN + j0];
        uint32_t r0, r1;
        tf2x32(skey[4], skey[5], 0u, (uint32_t)(g*NN*NN + i*NN + j0), r0, r1);
        bool pred = (j0 < i) && ((int)((r0 ^ r1) >> 9) > t);
        unsigned long long m = __ballot(pred);
        if (lane == 0) Abits[i*9 + 2*jw]     = (uint32_t)m;
        if (lane == 1) Abits[i*9 + 2*jw + 1] = (uint32_t)(m >> 32);
      }
    }
  }
  __syncthreads();

  // ---- phase 2b/2c: A = L | L^T via 32x32 shuffle bit-transpose ----
  {
    int l31 = lane & 31, half = lane >> 5;
    uint32_t tw[4];
    const uint32_t msk[5] = {0xFFFF0000u, 0xFF00FF00u, 0xF0F0F0F0u, 0xCCCCCCCCu, 0xAAAAAAAAu};
    #pragma unroll
    for (int p = 0; p < 4; ++p){
      int t = wvid*8 + p*2 + half;       // tile 0..63
      int I = t >> 3, J = t & 7;
      uint32_t x = Abits[(I*32 + l31)*9 + J];
      #pragma unroll
      for (int s = 0; s < 5; ++s){
        int k = 16 >> s;
        uint32_t mh = msk[s];
        uint32_t y = __shfl_xor(x, k, 64);
        x = (lane & k) ? ((x & mh) | ((y >> k) & ~mh))
                       : ((x & ~mh) | ((y << k) & mh));
      }
      tw[p] = x;
    }
    __syncthreads();
    #pragma unroll
    for (int p = 0; p < 4; ++p){
      int t = wvid*8 + p*2 + half;
      int I = t >> 3, J = t & 7;
      Abits[(J*32 + l31)*9 + I] |= tw[p];
    }
  }
  __syncthreads();

  // ---- phase 3: AZ = A @ Zs via MFMA -> azb (bf16) ----
  #pragma unroll
  for (int rr = 0; rr < 2; ++rr){
    int rt = wvid*2 + rr;
    int row = rt*16 + l15;
    float4v acc0 = {0.f,0.f,0.f,0.f}, acc1 = {0.f,0.f,0.f,0.f};
    #pragma unroll
    for (int c = 0; c < 8; ++c){
      uint32_t byte = (Abits[row*9 + c] >> (l4*8)) & 0xFFu;
      short8v af;
      #pragma unroll
      for (int b = 0; b < 8; ++b) af[b] = (short)(((byte >> b) & 1u) * 0x3F80u);
      short8v b0 = *(const short8v*)&zT[l15][c*32 + l4*8];
      short8v b1 = *(const short8v*)&zT[16 + l15][c*32 + l4*8];
      acc0 = __builtin_amdgcn_mfma_f32_16x16x32_bf16(af, b0, acc0, 0, 0, 0);
      acc1 = __builtin_amdgcn_mfma_f32_16x16x32_bf16(af, b1, acc1, 0, 0, 0);
    }
    #pragma unroll
    for (int r2 = 0; r2 < 4; ++r2){
      azb[rt*16 + l4*4 + r2][l15]      = f2bf(acc0[r2]);
      azb[rt*16 + l4*4 + r2][16 + l15] = f2bf(acc1[r2]);
    }
  }
  __syncthreads();

  // ---- phase 4: h^T = relu(AZ @ Wd1 + bd1)^T via MFMA -> zT ----
  {
    short8v bf0 = *(const short8v*)&wd1T[l15*40 + l4*8];
    short8v bf1 = *(const short8v*)&wd1T[(16 + l15)*40 + l4*8];
    float bb0 = bd1s[l15], bb1 = bd1s[16 + l15];
    #pragma unroll
    for (int mt = 0; mt < 2; ++mt){
      int n0 = wvid*32 + mt*16;
      short8v af = *(const short8v*)&azb[n0 + l15][l4*8];
      float4v c0 = {bb0, bb0, bb0, bb0};
      float4v c1 = {bb1, bb1, bb1, bb1};
      c0 = __builtin_amdgcn_mfma_f32_16x16x32_bf16(af, bf0, c0, 0, 0, 0);
      c1 = __builtin_amdgcn_mfma_f32_16x16x32_bf16(af, bf1, c1, 0, 0, 0);
      int nb = n0 + l4*4;
      short4v p0, p1;
      #pragma unroll
      for (int r2 = 0; r2 < 4; ++r2){
        p0[r2] = (short)f2bf(fmaxf(c0[r2], 0.f));
        p1[r2] = (short)f2bf(fmaxf(c1[r2], 0.f));
      }
      *(short4v*)&zT[l15][nb] = p0;
      *(short4v*)&zT[16 + l15][nb] = p1;
    }
  }
  __syncthreads();

  // ---- phase 5: Ah = A @ h via MFMA -> azb (bf16) ----
  #pragma unroll
  for (int rr = 0; rr < 2; ++rr){
    int rt = wvid*2 + rr;
    int row = rt*16 + l15;
    float4v acc0 = {0.f,0.f,0.f,0.f}, acc1 = {0.f,0.f,0.f,0.f};
    #pragma unroll
    for (int c = 0; c < 8; ++c){
      uint32_t byte = (Abits[row*9 + c] >> (l4*8)) & 0xFFu;
      short8v af;
      #pragma unroll
      for (int b = 0; b < 8; ++b) af[b] = (short)(((byte >> b) & 1u) * 0x3F80u);
      short8v b0 = *(const short8v*)&zT[l15][c*32 + l4*8];
      short8v b1 = *(const short8v*)&zT[16 + l15][c*32 + l4*8];
      acc0 = __builtin_amdgcn_mfma_f32_16x16x32_bf16(af, b0, acc0, 0, 0, 0);
      acc1 = __builtin_amdgcn_mfma_f32_16x16x32_bf16(af, b1, acc1, 0, 0, 0);
    }
    #pragma unroll
    for (int r2 = 0; r2 < 4; ++r2){
      azb[rt*16 + l4*4 + r2][l15]      = f2bf(acc0[r2]);
      azb[rt*16 + l4*4 + r2][16 + l15] = f2bf(acc1[r2]);
    }
  }
  __syncthreads();

  // ---- phase 6: Xmu = Ah @ Wd2 + bd2 via MFMA ; squared error ; reduce ----
  float part = 0.f;
  {
    short8v bf0 = *(const short8v*)&wd2T[l15*40 + l4*8];
    short8v bf1 = *(const short8v*)&wd2T[(16 + l15)*40 + l4*8];
    float bb0 = bd2p[l15], bb1 = bd2p[16 + l15];
    #pragma unroll
    for (int mt = 0; mt < 2; ++mt){
      int n0 = wvid*32 + mt*16;
      short8v af = *(const short8v*)&azb[n0 + l15][l4*8];
      float4v c0 = {bb0, bb0, bb0, bb0};
      float4v c1 = {bb1, bb1, bb1, bb1};
      c0 = __builtin_amdgcn_mfma_f32_16x16x32_bf16(af, bf0, c0, 0, 0, 0);
      c1 = __builtin_amdgcn_mfma_f32_16x16x32_bf16(af, bf1, c1, 0, 0, 0);
      int nb = n0 + l4*4;
      #pragma unroll
      for (int r2 = 0; r2 < 4; ++r2){
        int n = nb + r2;
        float d0 = c0[r2] - X[((size_t)g*NN + n)*FF + l15];
        part = fmaf(d0, d0, part);
        if (l15 < FF - 16){
          float d1 = c1[r2] - X[((size_t)g*NN + n)*FF + 16 + l15];
          part = fmaf(d1, d1, part);
        }
      }
    }
  }
  float* red = (float*)Abits;
  red[tid] = part;
  __syncthreads();
  for (int s = 256; s > 0; s >>= 1){
    if (tid < s) red[tid] += red[tid + s];
    __syncthreads();
  }
  if (tid == 0) ws[W_PART + it*GG + g] = red[0];
}

// ---------- K5: final loss reduction ----------
__global__ void k_final(float* __restrict__ out, const float* __restrict__ ws){
  int tid = threadIdx.x;
  double s = 0.0;
  for (int i = tid; i < NS*GG; i += 512) s += (double)ws[W_PART + i];
  __shared__ double rd[512];
  rd[tid] = s;
  __syncthreads();
  for (int st = 256; st > 0; st >>= 1){
    if (tid < st) rd[tid] += rd[tid + st];
    __syncthreads();
  }
  if (tid == 0) out[O_LOSS] = (float)(rd[0] * (0.5/6400.0));
}

extern "C" void kernel_launch(void* const* d_in, const int* in_sizes, int n_in,
                              void* d_out, int out_size, void* d_ws, size_t ws_size,
                              hipStream_t stream){
  const float* X   = (const float*)d_in[0];
  const float* Wz1 = (const float*)d_in[1];
  const float* bz1 = (const float*)d_in[2];
  const float* Wz2 = (const float*)d_in[3];
  const float* bz2 = (const float*)d_in[4];
  const float* Wa1 = (const float*)d_in[5];
  const float* ba1 = (const float*)d_in[6];
  const float* Wth = (const float*)d_in[7];
  const float* Wal = (const float*)d_in[8];
  const float* bal = (const float*)d_in[9];
  const float* Wd1 = (const float*)d_in[10];
  const float* bd1 = (const float*)d_in[11];
  const float* Wd2 = (const float*)d_in[12];
  const float* bd2 = (const float*)d_in[13];
  const int* seed  = (const int*)d_in[14];
  float* out = (float*)d_out;
  float* ws  = (float*)d_ws;

  hipLaunchKernelGGL(k_encode, dim3(32,64), dim3(256), 0, stream,
                     X, Wz1, bz1, Wz2, bz2, Wa1, ba1, out, ws);
  hipLaunchKernelGGL(k_alpha, dim3(64), dim3(256), 0, stream, Wal, bal, out, ws);
  hipLaunchKernelGGL(k_theta, dim3(16,16,64), dim3(256), 0, stream, Wth, out, ws);
  hipLaunchKernelGGL(k_loop, dim3(64,100), dim3(512), 0, stream,
                     Wd1, bd1, Wd2, bd2, X, seed, out, ws);
  hipLaunchKernelGGL(k_final, dim3(1), dim3(512), 0, stream, out, ws);
}

// Round 4
// 1813.156 us; speedup vs baseline: 1.1288x; 1.1288x over previous
//
#include <hip/hip_runtime.h>
#include <stdint.h>

#define GG 64
#define NN 256
#define FF 20
#define HH 32
#define KK 5
#define NS 100

// out offsets (floats)
#define O_PT   0
#define O_LA   20971520
#define O_ZMU  20971840
#define O_LOSS 21496128

// ws offsets (floats/ints)
#define W_HA   0
#define W_LT   524288          /* [K][G][N][N] int mantissa-threshold */
#define W_PART 21495808        /* [NS*G] */

typedef __attribute__((ext_vector_type(8))) short short8v;
typedef __attribute__((ext_vector_type(4))) short short4v;
typedef __attribute__((ext_vector_type(4))) float float4v;

__device__ __forceinline__ uint32_t rotl32(uint32_t v, int n){ return (v << n) | (v >> (32 - n)); }

// JAX threefry2x32 (20 rounds), key (k0,k1), counter (x0,x1)
__device__ __forceinline__ void tf2x32(uint32_t k0, uint32_t k1, uint32_t x0, uint32_t x1,
                                       uint32_t& o0, uint32_t& o1){
  uint32_t k2 = k0 ^ k1 ^ 0x1BD11BDAu;
  x0 += k0; x1 += k1;
  x0 += x1; x1 = rotl32(x1,13); x1 ^= x0;
  x0 += x1; x1 = rotl32(x1,15); x1 ^= x0;
  x0 += x1; x1 = rotl32(x1,26); x1 ^= x0;
  x0 += x1; x1 = rotl32(x1, 6); x1 ^= x0;
  x0 += k1; x1 += k2 + 1u;
  x0 += x1; x1 = rotl32(x1,17); x1 ^= x0;
  x0 += x1; x1 = rotl32(x1,29); x1 ^= x0;
  x0 += x1; x1 = rotl32(x1,16); x1 ^= x0;
  x0 += x1; x1 = rotl32(x1,24); x1 ^= x0;
  x0 += k2; x1 += k0 + 2u;
  x0 += x1; x1 = rotl32(x1,13); x1 ^= x0;
  x0 += x1; x1 = rotl32(x1,15); x1 ^= x0;
  x0 += x1; x1 = rotl32(x1,26); x1 ^= x0;
  x0 += x1; x1 = rotl32(x1, 6); x1 ^= x0;
  x0 += k0; x1 += k1 + 3u;
  x0 += x1; x1 = rotl32(x1,17); x1 ^= x0;
  x0 += x1; x1 = rotl32(x1,29); x1 ^= x0;
  x0 += x1; x1 = rotl32(x1,16); x1 ^= x0;
  x0 += x1; x1 = rotl32(x1,24); x1 ^= x0;
  x0 += k1; x1 += k2 + 4u;
  x0 += x1; x1 = rotl32(x1,13); x1 ^= x0;
  x0 += x1; x1 = rotl32(x1,15); x1 ^= x0;
  x0 += x1; x1 = rotl32(x1,26); x1 ^= x0;
  x0 += x1; x1 = rotl32(x1, 6); x1 ^= x0;
  o0 = x0 + k2; o1 = x1 + k0 + 5u;
}

// dual-chain threefry: two independent hashes interleaved for ILP (x0=0 for both)
#define TFR2(r) xa0 += xa1; xb0 += xb1; xa1 = rotl32(xa1,r); xb1 = rotl32(xb1,r); xa1 ^= xa0; xb1 ^= xb0;
__device__ __forceinline__ void tf2x32_pair(uint32_t k0, uint32_t k1, uint32_t ea, uint32_t eb,
                                            uint32_t& ao0, uint32_t& ao1,
                                            uint32_t& bo0, uint32_t& bo1){
  uint32_t k2 = k0 ^ k1 ^ 0x1BD11BDAu;
  uint32_t xa0 = k0, xa1 = ea + k1;
  uint32_t xb0 = k0, xb1 = eb + k1;
  TFR2(13) TFR2(15) TFR2(26) TFR2(6)
  xa0 += k1; xb0 += k1; xa1 += k2 + 1u; xb1 += k2 + 1u;
  TFR2(17) TFR2(29) TFR2(16) TFR2(24)
  xa0 += k2; xb0 += k2; xa1 += k0 + 2u; xb1 += k0 + 2u;
  TFR2(13) TFR2(15) TFR2(26) TFR2(6)
  xa0 += k0; xb0 += k0; xa1 += k1 + 3u; xb1 += k1 + 3u;
  TFR2(17) TFR2(29) TFR2(16) TFR2(24)
  xa0 += k1; xb0 += k1; xa1 += k2 + 4u; xb1 += k2 + 4u;
  TFR2(13) TFR2(15) TFR2(26) TFR2(6)
  ao0 = xa0 + k2; bo0 = xb0 + k2;
  ao1 = xa1 + k0 + 5u; bo1 = xb1 + k0 + 5u;
}

__device__ __forceinline__ float u01(uint32_t b){
  return __uint_as_float((b >> 9) | 0x3f800000u) - 1.0f;
}

__device__ __forceinline__ unsigned short f2bf(float f){
  uint32_t u = __float_as_uint(f);
  uint32_t r = u + 0x7FFFu + ((u >> 16) & 1u);
  return (unsigned short)(r >> 16);
}

// XLA ErfInv32 (Giles 2012)
__device__ __forceinline__ float erfinv_f(float x){
  float w = -log1pf(-x*x);
  float p;
  if (w < 5.f){
    w = w - 2.5f;
    p = 2.81022636e-08f;
    p = fmaf(p,w, 3.43273939e-07f);
    p = fmaf(p,w,-3.5233877e-06f);
    p = fmaf(p,w,-4.39150654e-06f);
    p = fmaf(p,w, 0.00021858087f);
    p = fmaf(p,w,-0.00125372503f);
    p = fmaf(p,w,-0.00417768164f);
    p = fmaf(p,w, 0.246640727f);
    p = fmaf(p,w, 1.50140941f);
  } else {
    w = sqrtf(w) - 3.f;
    p = -0.000200214257f;
    p = fmaf(p,w, 0.000100950558f);
    p = fmaf(p,w, 0.00134934322f);
    p = fmaf(p,w,-0.00367342844f);
    p = fmaf(p,w, 0.00573950773f);
    p = fmaf(p,w,-0.0076224613f);
    p = fmaf(p,w, 0.00943887047f);
    p = fmaf(p,w, 1.00167406f);
    p = fmaf(p,w, 2.83297682f);
  }
  return p*x;
}

// group c (0..635) -> (row i, word-group jw): row i has ceil(i/64) 64-wide groups
__device__ __forceinline__ void gdecode(int c, int& i, int& jw){
  if (c < 64)      { i = c + 1; jw = 0; }
  else if (c < 192){ int q = c - 64;  i = 65  + (q >> 1); jw = q & 1; }
  else if (c < 384){ int q = c - 192; int d = q/3; i = 129 + d; jw = q - 3*d; }
  else             { int q = c - 384; i = 193 + (q >> 2); jw = q & 3; }
}

// ---------- K1: per-node encoders: Z_mu -> out, ha -> ws ----------
__global__ void k_encode(const float* __restrict__ X,
                         const float* __restrict__ Wz1, const float* __restrict__ bz1,
                         const float* __restrict__ Wz2, const float* __restrict__ bz2,
                         const float* __restrict__ Wa1, const float* __restrict__ ba1,
                         float* __restrict__ out, float* __restrict__ ws){
  int g = blockIdx.y, nt = blockIdx.x;   // nt 0..31 (8 nodes each)
  int tid = threadIdx.x;
  int nl = tid >> 5, h = tid & 31;
  __shared__ float xrow[8][FF];
  __shared__ float hzrow[8][HH];
  if (tid < 8*FF){
    int a = tid / FF, b = tid % FF;
    xrow[a][b] = X[(g*NN + nt*8 + a)*FF + b];
  }
  __syncthreads();
  float hz = bz1[h], ha = ba1[h];
  for (int f = 0; f < FF; ++f){
    float xv = xrow[nl][f];
    hz = fmaf(xv, Wz1[f*HH + h], hz);
    ha = fmaf(xv, Wa1[f*HH + h], ha);
  }
  hz = fmaxf(hz, 0.f); ha = fmaxf(ha, 0.f);
  hzrow[nl][h] = hz;
  int n = nt*8 + nl;
  ws[W_HA + (g*NN + n)*HH + h] = ha;
  __syncthreads();
  float zm = bz2[h];
  for (int hh = 0; hh < HH; ++hh)
    zm = fmaf(hzrow[nl][hh], Wz2[hh*HH + h], zm);
  out[O_ZMU + (g*NN + n)*HH + h] = zm;
}

// ---------- K2: logit_alpha = mean_n(ha) @ Walpha + balpha ----------
__global__ void k_alpha(const float* __restrict__ Walpha, const float* __restrict__ balpha,
                        float* __restrict__ out, const float* __restrict__ ws){
  int g = blockIdx.x; int tid = threadIdx.x;
  int h = tid & 31, p = tid >> 5;  // p 0..7
  __shared__ float sums[8][HH];
  __shared__ float meanh[HH];
  float s = 0.f;
  for (int n = p; n < NN; n += 8) s += ws[W_HA + (g*NN + n)*HH + h];
  sums[p][h] = s;
  __syncthreads();
  if (p == 0){
    float t = 0.f;
    for (int q = 0; q < 8; ++q) t += sums[q][h];
    meanh[h] = t * (1.0f/256.0f);
  }
  __syncthreads();
  if (tid < KK){
    float la = balpha[tid];
    for (int hh = 0; hh < HH; ++hh) la = fmaf(meanh[hh], Walpha[hh*KK + tid], la);
    out[O_LA + g*KK + tid] = la;
  }
}

// ---------- K3: prob_theta (out) + int mantissa threshold (ws, k-major) ----------
__global__ void k_theta(const float* __restrict__ Wtheta,
                        float* __restrict__ out, float* __restrict__ ws){
  int jt = blockIdx.x, it = blockIdx.y, g = blockIdx.z;
  int tid = threadIdx.x;
  __shared__ float wth[HH*HH*KK];     // [h][f*K+k]
  __shared__ float hai[16][HH], haj[16][HH];
  __shared__ float tloc[16][HH*KK];   // [i][f*K+k]
  for (int idx = tid; idx < HH*HH*KK; idx += 256) wth[idx] = Wtheta[idx];
  for (int idx = tid; idx < 16*HH; idx += 256){
    int r = idx >> 5, c = idx & 31;
    hai[r][c] = ws[W_HA + (g*NN + it*16 + r)*HH + c];
    haj[r][c] = ws[W_HA + (g*NN + jt*16 + r)*HH + c];
  }
  __syncthreads();
  for (int idx = tid; idx < 16*HH*KK; idx += 256){
    int i = idx / (HH*KK), rem = idx % (HH*KK);
    float a = 0.f;
    for (int hh = 0; hh < HH; ++hh) a = fmaf(hai[i][hh], wth[hh*(HH*KK) + rem], a);
    tloc[i][rem] = a;
  }
  __syncthreads();
  int il = tid >> 4, jl = tid & 15;
  float acc[KK] = {0,0,0,0,0};
  for (int f = 0; f < HH; ++f){
    float hv = haj[jl][f];
    #pragma unroll
    for (int k = 0; k < KK; ++k) acc[k] = fmaf(tloc[il][f*KK+k], hv, acc[k]);
  }
  int i = it*16 + il, j = jt*16 + jl;
  int* tint = (int*)ws;
  #pragma unroll
  for (int k = 0; k < KK; ++k){
    float v = acc[k];
    float s = 1.f / (1.f + expf(-v));
    float thrf = 1.f - s;                            // sigmoid(-v)
    float fthr = (thrf - 1e-6f) * (1.f / (1.f - 2e-6f));
    int t;
    if (fthr <= 0.f) t = -1;
    else if (fthr >= 1.f) t = 0x7FFFFFFF;
    else t = (int)(__float_as_uint(1.0f + fthr) - 0x3f800000u);
    tint[W_LT + ((size_t)k*GG + g)*NN*NN + i*NN + j] = t;
    out[O_PT + ((size_t)(g*NN + i)*NN + j)*KK + k] = (i == j) ? 0.f : s;
  }
}

// ---------- K4: the whole MC loop, one block per (it, g) ----------
__global__ __launch_bounds__(512, 6)
void k_loop(const float* __restrict__ Wd1, const float* __restrict__ bd1,
            const float* __restrict__ Wd2, const float* __restrict__ bd2,
            const float* __restrict__ X, const int* __restrict__ seedp,
            const float* __restrict__ outro, float* __restrict__ ws){
  int g  = blockIdx.x;   // 0..63
  int it = blockIdx.y;   // 0..99
  int tid = threadIdx.x; // 0..511
  int lane = tid & 63, wvid = tid >> 6;
  int l15 = lane & 15, l4 = lane >> 4;

  __shared__ unsigned short zT[HH][264];   // bf16 Z^T then h^T        16.9KB
  __shared__ unsigned short azb[NN][40];   // bf16 AZ then Ah           20.5KB
  __shared__ uint32_t Abits[NN*9];         // adjacency bits, 9 w/row   9.2KB
  __shared__ unsigned short wd1T[HH*40];   // Wd1^T bf16 [m][k]         2.5KB
  __shared__ unsigned short wd2T[HH*40];   // Wd2^T bf16 padded [f][k]  2.5KB
  __shared__ float bd1s[HH], bd2p[HH];
  __shared__ short4v tab16[16];            // nibble -> 4 bf16 0/1      128B
  __shared__ float wsum[8];
  __shared__ uint32_t skey[6];
  __shared__ int skmax;

  // wave 0: derive keys + parallel gumbel argmax; other waves load weights
  if (wvid == 0){
    uint32_t seed = (uint32_t)(*seedp);
    uint32_t b0, b1, a0, a1, c0, c1, d0, d1;
    tf2x32(0u, seed, 0u, (uint32_t)it, b0, b1);  // fold_in(base, it)
    tf2x32(b0, b1, 0u, 0u, a0, a1);              // split -> k1
    tf2x32(b0, b1, 0u, 1u, c0, c1);              // k2
    tf2x32(b0, b1, 0u, 2u, d0, d1);              // k3
    float z = -3.4e38f;
    if (lane < KK){
      uint32_t e = (uint32_t)(g*KK + lane), r0, r1;
      tf2x32(c0, c1, 0u, e, r0, r1);
      float f = u01(r0 ^ r1);
      float u = fmaxf(1.17549435e-38f, f + 1.17549435e-38f);
      float gum = -logf(-logf(u));
      z = outro[O_LA + g*KK + lane] + gum;
    }
    float z0 = __shfl(z,0), z1 = __shfl(z,1), z2 = __shfl(z,2), z3 = __shfl(z,3), z4 = __shfl(z,4);
    if (lane == 0){
      skey[0]=a0; skey[1]=a1; skey[2]=c0; skey[3]=c1; skey[4]=d0; skey[5]=d1;
      float best = z0; int arg = 0;
      if (z1 > best){ best = z1; arg = 1; }
      if (z2 > best){ best = z2; arg = 2; }
      if (z3 > best){ best = z3; arg = 3; }
      if (z4 > best){ best = z4; arg = 4; }
      skmax = arg;
    }
  }
  for (int idx = tid; idx < HH*HH; idx += 512){
    int k = idx >> 5, m = idx & 31;
    wd1T[m*40 + k] = f2bf(Wd1[idx]);
    int f = m;
    wd2T[f*40 + k] = (f < FF) ? f2bf(Wd2[k*FF + f]) : 0;
  }
  if (tid < HH) bd1s[tid] = bd1[tid];
  if (tid < HH) bd2p[tid] = (tid < FF) ? bd2[tid] : 0.f;
  if (tid < 16){
    short4v t;
    #pragma unroll
    for (int b = 0; b < 4; ++b) t[b] = (short)(((tid >> b) & 1) * 0x3F80);
    tab16[tid] = t;
  }
  for (int idx = tid; idx < NN*9; idx += 512) Abits[idx] = 0u;
  __syncthreads();

  // ---- phase 1: sample_Z = Z_mu + std*normal -> zT (bf16, transposed) ----
  {
    uint32_t k0 = skey[0], k1 = skey[1];
    #pragma unroll
    for (int kk = 0; kk < 4; ++kk){
      int n = kk*64 + lane;
      #pragma unroll
      for (int hh = 0; hh < 4; ++hh){
        int h = wvid*4 + hh;
        uint32_t e = (uint32_t)(g*NN*HH + n*HH + h), r0, r1;
        tf2x32(k0, k1, 0u, e, r0, r1);
        float f = u01(r0 ^ r1);
        float u = fmaf(f, 2.0f, -0.99999994f);
        float nrm = 1.41421356f * erfinv_f(u);
        float zf = outro[O_ZMU + g*NN*HH + n*HH + h] + 0.22313016f * nrm;
        zT[h][n] = f2bf(zf);
      }
    }
  }

  // ---- phase 2a: ballot-built strict-lower adjacency rows (2 groups/iter) ----
  {
    uint32_t k4 = skey[4], k5 = skey[5];
    const int* tintp = (const int*)ws + W_LT + ((size_t)skmax*GG + g)*NN*NN;
    int ebase = g*NN*NN;
    for (int c = wvid*2; c < 636; c += 16){
      int ia, ja, ib, jb;
      gdecode(c, ia, ja);
      gdecode(c + 1, ib, jb);
      int j0a = ja*64 + lane, j0b = jb*64 + lane;
      int ta = tintp[ia*NN + j0a];
      int tb = tintp[ib*NN + j0b];
      uint32_t a0, a1, b0, b1;
      tf2x32_pair(k4, k5, (uint32_t)(ebase + ia*NN + j0a), (uint32_t)(ebase + ib*NN + j0b),
                  a0, a1, b0, b1);
      unsigned long long ma = __ballot((j0a < ia) && ((int)((a0 ^ a1) >> 9) > ta));
      unsigned long long mb = __ballot((j0b < ib) && ((int)((b0 ^ b1) >> 9) > tb));
      if (lane == 0){ Abits[ia*9 + 2*ja] = (uint32_t)ma; Abits[ib*9 + 2*jb] = (uint32_t)mb; }
      if (lane == 1){ Abits[ia*9 + 2*ja + 1] = (uint32_t)(ma >> 32); Abits[ib*9 + 2*jb + 1] = (uint32_t)(mb >> 32); }
    }
  }
  __syncthreads();

  // ---- phase 2b: A = L | L^T via 32x32 shuffle bit-transpose ----
  {
    int l31 = lane & 31, half = lane >> 5;
    uint32_t tw[4];
    const uint32_t msk[5] = {0xFFFF0000u, 0xFF00FF00u, 0xF0F0F0F0u, 0xCCCCCCCCu, 0xAAAAAAAAu};
    #pragma unroll
    for (int p = 0; p < 4; ++p){
      int t = wvid*8 + p*2 + half;       // tile 0..63
      int I = t >> 3, J = t & 7;
      uint32_t x = Abits[(I*32 + l31)*9 + J];
      #pragma unroll
      for (int s = 0; s < 5; ++s){
        int k = 16 >> s;
        uint32_t mh = msk[s];
        uint32_t y = __shfl_xor(x, k, 64);
        x = (lane & k) ? ((x & mh) | ((y >> k) & ~mh))
                       : ((x & ~mh) | ((y << k) & mh));
      }
      tw[p] = x;
    }
    __syncthreads();
    #pragma unroll
    for (int p = 0; p < 4; ++p){
      int t = wvid*8 + p*2 + half;
      int I = t >> 3, J = t & 7;
      Abits[(J*32 + l31)*9 + I] |= tw[p];
    }
  }
  __syncthreads();

  // ---- phase 3: AZ = A @ Zs via MFMA -> azb (bf16) ----
  #pragma unroll
  for (int rr = 0; rr < 2; ++rr){
    int rt = wvid*2 + rr;
    int row = rt*16 + l15;
    float4v acc0 = {0.f,0.f,0.f,0.f}, acc1 = {0.f,0.f,0.f,0.f};
    #pragma unroll
    for (int c = 0; c < 8; ++c){
      uint32_t byte = (Abits[row*9 + c] >> (l4*8)) & 0xFFu;
      short4v lo = tab16[byte & 15u];
      short4v hi = tab16[byte >> 4];
      short8v af = {lo[0],lo[1],lo[2],lo[3],hi[0],hi[1],hi[2],hi[3]};
      short8v b0 = *(const short8v*)&zT[l15][c*32 + l4*8];
      short8v b1 = *(const short8v*)&zT[16 + l15][c*32 + l4*8];
      acc0 = __builtin_amdgcn_mfma_f32_16x16x32_bf16(af, b0, acc0, 0, 0, 0);
      acc1 = __builtin_amdgcn_mfma_f32_16x16x32_bf16(af, b1, acc1, 0, 0, 0);
    }
    #pragma unroll
    for (int r2 = 0; r2 < 4; ++r2){
      azb[rt*16 + l4*4 + r2][l15]      = f2bf(acc0[r2]);
      azb[rt*16 + l4*4 + r2][16 + l15] = f2bf(acc1[r2]);
    }
  }
  __syncthreads();

  // ---- phase 4: h^T = relu(AZ @ Wd1 + bd1)^T via MFMA -> zT ----
  {
    short8v bf0 = *(const short8v*)&wd1T[l15*40 + l4*8];
    short8v bf1 = *(const short8v*)&wd1T[(16 + l15)*40 + l4*8];
    float bb0 = bd1s[l15], bb1 = bd1s[16 + l15];
    #pragma unroll
    for (int mt = 0; mt < 2; ++mt){
      int n0 = wvid*32 + mt*16;
      short8v af = *(const short8v*)&azb[n0 + l15][l4*8];
      float4v c0 = {bb0, bb0, bb0, bb0};
      float4v c1 = {bb1, bb1, bb1, bb1};
      c0 = __builtin_amdgcn_mfma_f32_16x16x32_bf16(af, bf0, c0, 0, 0, 0);
      c1 = __builtin_amdgcn_mfma_f32_16x16x32_bf16(af, bf1, c1, 0, 0, 0);
      int nb = n0 + l4*4;
      short4v p0, p1;
      #pragma unroll
      for (int r2 = 0; r2 < 4; ++r2){
        p0[r2] = (short)f2bf(fmaxf(c0[r2], 0.f));
        p1[r2] = (short)f2bf(fmaxf(c1[r2], 0.f));
      }
      *(short4v*)&zT[l15][nb] = p0;
      *(short4v*)&zT[16 + l15][nb] = p1;
    }
  }
  __syncthreads();

  // ---- phase 5: Ah = A @ h via MFMA -> azb (bf16) ----
  #pragma unroll
  for (int rr = 0; rr < 2; ++rr){
    int rt = wvid*2 + rr;
    int row = rt*16 + l15;
    float4v acc0 = {0.f,0.f,0.f,0.f}, acc1 = {0.f,0.f,0.f,0.f};
    #pragma unroll
    for (int c = 0; c < 8; ++c){
      uint32_t byte = (Abits[row*9 + c] >> (l4*8)) & 0xFFu;
      short4v lo = tab16[byte & 15u];
      short4v hi = tab16[byte >> 4];
      short8v af = {lo[0],lo[1],lo[2],lo[3],hi[0],hi[1],hi[2],hi[3]};
      short8v b0 = *(const short8v*)&zT[l15][c*32 + l4*8];
      short8v b1 = *(const short8v*)&zT[16 + l15][c*32 + l4*8];
      acc0 = __builtin_amdgcn_mfma_f32_16x16x32_bf16(af, b0, acc0, 0, 0, 0);
      acc1 = __builtin_amdgcn_mfma_f32_16x16x32_bf16(af, b1, acc1, 0, 0, 0);
    }
    #pragma unroll
    for (int r2 = 0; r2 < 4; ++r2){
      azb[rt*16 + l4*4 + r2][l15]      = f2bf(acc0[r2]);
      azb[rt*16 + l4*4 + r2][16 + l15] = f2bf(acc1[r2]);
    }
  }
  __syncthreads();

  // ---- phase 6: Xmu = Ah @ Wd2 + bd2 via MFMA ; squared error ; reduce ----
  float part = 0.f;
  {
    short8v bf0 = *(const short8v*)&wd2T[l15*40 + l4*8];
    short8v bf1 = *(const short8v*)&wd2T[(16 + l15)*40 + l4*8];
    float bb0 = bd2p[l15], bb1 = bd2p[16 + l15];
    #pragma unroll
    for (int mt = 0; mt < 2; ++mt){
      int n0 = wvid*32 + mt*16;
      short8v af = *(const short8v*)&azb[n0 + l15][l4*8];
      float4v c0 = {bb0, bb0, bb0, bb0};
      float4v c1 = {bb1, bb1, bb1, bb1};
      c0 = __builtin_amdgcn_mfma_f32_16x16x32_bf16(af, bf0, c0, 0, 0, 0);
      c1 = __builtin_amdgcn_mfma_f32_16x16x32_bf16(af, bf1, c1, 0, 0, 0);
      int nb = n0 + l4*4;
      #pragma unroll
      for (int r2 = 0; r2 < 4; ++r2){
        int n = nb + r2;
        float d0 = c0[r2] - X[((size_t)g*NN + n)*FF + l15];
        part = fmaf(d0, d0, part);
        if (l15 < FF - 16){
          float d1 = c1[r2] - X[((size_t)g*NN + n)*FF + 16 + l15];
          part = fmaf(d1, d1, part);
        }
      }
    }
  }
  // wave-level shuffle reduce, then single cross-wave pass
  #pragma unroll
  for (int off = 32; off > 0; off >>= 1) part += __shfl_down(part, off);
  if (lane == 0) wsum[wvid] = part;
  __syncthreads();
  if (tid == 0){
    float s = 0.f;
    #pragma unroll
    for (int wq = 0; wq < 8; ++wq) s += wsum[wq];
    ws[W_PART + it*GG + g] = s;
  }
}

// ---------- K5: final loss reduction ----------
__global__ void k_final(float* __restrict__ out, const float* __restrict__ ws){
  int tid = threadIdx.x;
  double s = 0.0;
  for (int i = tid; i < NS*GG; i += 512) s += (double)ws[W_PART + i];
  __shared__ double rd[512];
  rd[tid] = s;
  __syncthreads();
  for (int st = 256; st > 0; st >>= 1){
    if (tid < st) rd[tid] += rd[tid + st];
    __syncthreads();
  }
  if (tid == 0) out[O_LOSS] = (float)(rd[0] * (0.5/6400.0));
}

extern "C" void kernel_launch(void* const* d_in, const int* in_sizes, int n_in,
                              void* d_out, int out_size, void* d_ws, size_t ws_size,
                              hipStream_t stream){
  const float* X   = (const float*)d_in[0];
  const float* Wz1 = (const float*)d_in[1];
  const float* bz1 = (const float*)d_in[2];
  const float* Wz2 = (const float*)d_in[3];
  const float* bz2 = (const float*)d_in[4];
  const float* Wa1 = (const float*)d_in[5];
  const float* ba1 = (const float*)d_in[6];
  const float* Wth = (const float*)d_in[7];
  const float* Wal = (const float*)d_in[8];
  const float* bal = (const float*)d_in[9];
  const float* Wd1 = (const float*)d_in[10];
  const float* bd1 = (const float*)d_in[11];
  const float* Wd2 = (const float*)d_in[12];
  const float* bd2 = (const float*)d_in[13];
  const int* seed  = (const int*)d_in[14];
  float* out = (float*)d_out;
  float* ws  = (float*)d_ws;

  hipLaunchKernelGGL(k_encode, dim3(32,64), dim3(256), 0, stream,
                     X, Wz1, bz1, Wz2, bz2, Wa1, ba1, out, ws);
  hipLaunchKernelGGL(k_alpha, dim3(64), dim3(256), 0, stream, Wal, bal, out, ws);
  hipLaunchKernelGGL(k_theta, dim3(16,16,64), dim3(256), 0, stream, Wth, out, ws);
  hipLaunchKernelGGL(k_loop, dim3(64,100), dim3(512), 0, stream,
                     Wd1, bd1, Wd2, bd2, X, seed, out, ws);
  hipLaunchKernelGGL(k_final, dim3(1), dim3(512), 0, stream, out, ws);
}

// Round 5
// 1292.354 us; speedup vs baseline: 1.5837x; 1.4030x over previous
//
#include <hip/hip_runtime.h>
#include <stdint.h>

#define GG 64
#define NN 256
#define FF 20
#define HH 32
#define KK 5
#define NS 100

// out offsets (floats)
#define O_PT   0
#define O_LA   20971520
#define O_ZMU  20971840
#define O_LOSS 21496128

// ws offsets (floats/ints)
#define W_HA   0
#define W_LT   524288          /* [K][G][N][N] int mantissa-threshold */
#define W_PART 21495808        /* [NS*G] */

typedef __attribute__((ext_vector_type(8))) short short8v;
typedef __attribute__((ext_vector_type(4))) short short4v;
typedef __attribute__((ext_vector_type(4))) float float4v;

__device__ __forceinline__ uint32_t rotl32(uint32_t v, int n){ return (v << n) | (v >> (32 - n)); }

// JAX threefry2x32 (20 rounds) — used only for key derivation + gumbel (bit-exact)
__device__ __forceinline__ void tf2x32(uint32_t k0, uint32_t k1, uint32_t x0, uint32_t x1,
                                       uint32_t& o0, uint32_t& o1){
  uint32_t k2 = k0 ^ k1 ^ 0x1BD11BDAu;
  x0 += k0; x1 += k1;
  x0 += x1; x1 = rotl32(x1,13); x1 ^= x0;
  x0 += x1; x1 = rotl32(x1,15); x1 ^= x0;
  x0 += x1; x1 = rotl32(x1,26); x1 ^= x0;
  x0 += x1; x1 = rotl32(x1, 6); x1 ^= x0;
  x0 += k1; x1 += k2 + 1u;
  x0 += x1; x1 = rotl32(x1,17); x1 ^= x0;
  x0 += x1; x1 = rotl32(x1,29); x1 ^= x0;
  x0 += x1; x1 = rotl32(x1,16); x1 ^= x0;
  x0 += x1; x1 = rotl32(x1,24); x1 ^= x0;
  x0 += k2; x1 += k0 + 2u;
  x0 += x1; x1 = rotl32(x1,13); x1 ^= x0;
  x0 += x1; x1 = rotl32(x1,15); x1 ^= x0;
  x0 += x1; x1 = rotl32(x1,26); x1 ^= x0;
  x0 += x1; x1 = rotl32(x1, 6); x1 ^= x0;
  x0 += k0; x1 += k1 + 3u;
  x0 += x1; x1 = rotl32(x1,17); x1 ^= x0;
  x0 += x1; x1 = rotl32(x1,29); x1 ^= x0;
  x0 += x1; x1 = rotl32(x1,16); x1 ^= x0;
  x0 += x1; x1 = rotl32(x1,24); x1 ^= x0;
  x0 += k1; x1 += k2 + 4u;
  x0 += x1; x1 = rotl32(x1,13); x1 ^= x0;
  x0 += x1; x1 = rotl32(x1,15); x1 ^= x0;
  x0 += x1; x1 = rotl32(x1,26); x1 ^= x0;
  x0 += x1; x1 = rotl32(x1, 6); x1 ^= x0;
  o0 = x0 + k2; o1 = x1 + k0 + 5u;
}

// fast counter hash: double murmur3 finalizer, salted with JAX-derived keys.
// Statistically-equivalent replacement for threefry where bit-exactness is not
// needed (continuous noise / Bernoulli draws averaged over 6400 MC samples).
__device__ __forceinline__ uint32_t mmhash(uint32_t e, uint32_t ka, uint32_t kb){
  uint32_t x = e + ka;
  x ^= x >> 16; x *= 0x85EBCA6Bu; x ^= x >> 13; x *= 0xC2B2AE35u; x ^= x >> 16;
  x ^= kb;
  x ^= x >> 16; x *= 0x85EBCA6Bu; x ^= x >> 13; x *= 0xC2B2AE35u; x ^= x >> 16;
  return x;
}

__device__ __forceinline__ float u01(uint32_t b){
  return __uint_as_float((b >> 9) | 0x3f800000u) - 1.0f;
}

__device__ __forceinline__ unsigned short f2bf(float f){
  uint32_t u = __float_as_uint(f);
  uint32_t r = u + 0x7FFFu + ((u >> 16) & 1u);
  return (unsigned short)(r >> 16);
}

// ---------- K1: per-node encoders: Z_mu -> out, ha -> ws ----------
__global__ void k_encode(const float* __restrict__ X,
                         const float* __restrict__ Wz1, const float* __restrict__ bz1,
                         const float* __restrict__ Wz2, const float* __restrict__ bz2,
                         const float* __restrict__ Wa1, const float* __restrict__ ba1,
                         float* __restrict__ out, float* __restrict__ ws){
  int g = blockIdx.y, nt = blockIdx.x;   // nt 0..31 (8 nodes each)
  int tid = threadIdx.x;
  int nl = tid >> 5, h = tid & 31;
  __shared__ float xrow[8][FF];
  __shared__ float hzrow[8][HH];
  if (tid < 8*FF){
    int a = tid / FF, b = tid % FF;
    xrow[a][b] = X[(g*NN + nt*8 + a)*FF + b];
  }
  __syncthreads();
  float hz = bz1[h], ha = ba1[h];
  for (int f = 0; f < FF; ++f){
    float xv = xrow[nl][f];
    hz = fmaf(xv, Wz1[f*HH + h], hz);
    ha = fmaf(xv, Wa1[f*HH + h], ha);
  }
  hz = fmaxf(hz, 0.f); ha = fmaxf(ha, 0.f);
  hzrow[nl][h] = hz;
  int n = nt*8 + nl;
  ws[W_HA + (g*NN + n)*HH + h] = ha;
  __syncthreads();
  float zm = bz2[h];
  for (int hh = 0; hh < HH; ++hh)
    zm = fmaf(hzrow[nl][hh], Wz2[hh*HH + h], zm);
  out[O_ZMU + (g*NN + n)*HH + h] = zm;
}

// ---------- K2: logit_alpha = mean_n(ha) @ Walpha + balpha ----------
__global__ void k_alpha(const float* __restrict__ Walpha, const float* __restrict__ balpha,
                        float* __restrict__ out, const float* __restrict__ ws){
  int g = blockIdx.x; int tid = threadIdx.x;
  int h = tid & 31, p = tid >> 5;  // p 0..7
  __shared__ float sums[8][HH];
  __shared__ float meanh[HH];
  float s = 0.f;
  for (int n = p; n < NN; n += 8) s += ws[W_HA + (g*NN + n)*HH + h];
  sums[p][h] = s;
  __syncthreads();
  if (p == 0){
    float t = 0.f;
    for (int q = 0; q < 8; ++q) t += sums[q][h];
    meanh[h] = t * (1.0f/256.0f);
  }
  __syncthreads();
  if (tid < KK){
    float la = balpha[tid];
    for (int hh = 0; hh < HH; ++hh) la = fmaf(meanh[hh], Walpha[hh*KK + tid], la);
    out[O_LA + g*KK + tid] = la;
  }
}

// ---------- K3: prob_theta (out) + int mantissa threshold (ws, k-major) ----------
__global__ void k_theta(const float* __restrict__ Wtheta,
                        float* __restrict__ out, float* __restrict__ ws){
  int jt = blockIdx.x, it = blockIdx.y, g = blockIdx.z;
  int tid = threadIdx.x;
  __shared__ float wth[HH*HH*KK];     // [h][f*K+k]
  __shared__ float hai[16][HH], haj[16][HH];
  __shared__ float tloc[16][HH*KK];   // [i][f*K+k]
  for (int idx = tid; idx < HH*HH*KK; idx += 256) wth[idx] = Wtheta[idx];
  for (int idx = tid; idx < 16*HH; idx += 256){
    int r = idx >> 5, c = idx & 31;
    hai[r][c] = ws[W_HA + (g*NN + it*16 + r)*HH + c];
    haj[r][c] = ws[W_HA + (g*NN + jt*16 + r)*HH + c];
  }
  __syncthreads();
  for (int idx = tid; idx < 16*HH*KK; idx += 256){
    int i = idx / (HH*KK), rem = idx % (HH*KK);
    float a = 0.f;
    for (int hh = 0; hh < HH; ++hh) a = fmaf(hai[i][hh], wth[hh*(HH*KK) + rem], a);
    tloc[i][rem] = a;
  }
  __syncthreads();
  int il = tid >> 4, jl = tid & 15;
  float acc[KK] = {0,0,0,0,0};
  for (int f = 0; f < HH; ++f){
    float hv = haj[jl][f];
    #pragma unroll
    for (int k = 0; k < KK; ++k) acc[k] = fmaf(tloc[il][f*KK+k], hv, acc[k]);
  }
  int i = it*16 + il, j = jt*16 + jl;
  int* tint = (int*)ws;
  #pragma unroll
  for (int k = 0; k < KK; ++k){
    float v = acc[k];
    float s = 1.f / (1.f + expf(-v));
    float thrf = 1.f - s;                            // sigmoid(-v)
    float fthr = (thrf - 1e-6f) * (1.f / (1.f - 2e-6f));
    int t;
    if (fthr <= 0.f) t = -1;
    else if (fthr >= 1.f) t = 0x7FFFFFFF;
    else t = (int)(__float_as_uint(1.0f + fthr) - 0x3f800000u);
    tint[W_LT + ((size_t)k*GG + g)*NN*NN + i*NN + j] = t;
    out[O_PT + ((size_t)(g*NN + i)*NN + j)*KK + k] = (i == j) ? 0.f : s;
  }
}

// ---------- K4: the whole MC loop, one block per (it, g) ----------
__global__ __launch_bounds__(512, 6)
void k_loop(const float* __restrict__ Wd1, const float* __restrict__ bd1,
            const float* __restrict__ Wd2, const float* __restrict__ bd2,
            const float* __restrict__ X, const int* __restrict__ seedp,
            const float* __restrict__ outro, float* __restrict__ ws){
  int g  = blockIdx.x;   // 0..63
  int it = blockIdx.y;   // 0..99
  int tid = threadIdx.x; // 0..511
  int lane = tid & 63, wvid = tid >> 6;
  int l15 = lane & 15, l4 = lane >> 4;

  __shared__ unsigned short zT[HH][264];   // bf16 Z^T then h^T        16.9KB
  __shared__ unsigned short azb[NN][40];   // bf16 AZ then Ah           20.5KB
  __shared__ uint32_t Abits[NN*9];         // adjacency bits, 9 w/row   9.2KB
  __shared__ unsigned short wd1T[HH*40];   // Wd1^T bf16 [m][k]         2.5KB
  __shared__ unsigned short wd2T[HH*40];   // Wd2^T bf16 padded [f][k]  2.5KB
  __shared__ unsigned short ctab[636];     // ballot group table        1.27KB
  __shared__ float bd1s[HH], bd2p[HH];
  __shared__ short4v tab16[16];            // nibble -> 4 bf16 0/1      128B
  __shared__ float wsum[8];
  __shared__ uint32_t skey[6];
  __shared__ int skmax;

  // wave 0: derive keys (bit-exact threefry) + parallel gumbel argmax
  if (wvid == 0){
    uint32_t seed = (uint32_t)(*seedp);
    uint32_t b0, b1, a0, a1, c0, c1, d0, d1;
    tf2x32(0u, seed, 0u, (uint32_t)it, b0, b1);  // fold_in(base, it)
    tf2x32(b0, b1, 0u, 0u, a0, a1);              // split -> k1
    tf2x32(b0, b1, 0u, 1u, c0, c1);              // k2
    tf2x32(b0, b1, 0u, 2u, d0, d1);              // k3
    float z = -3.4e38f;
    if (lane < KK){
      uint32_t e = (uint32_t)(g*KK + lane), r0, r1;
      tf2x32(c0, c1, 0u, e, r0, r1);
      float f = u01(r0 ^ r1);
      float u = fmaxf(1.17549435e-38f, f + 1.17549435e-38f);
      float gum = -logf(-logf(u));
      z = outro[O_LA + g*KK + lane] + gum;
    }
    float z0 = __shfl(z,0), z1 = __shfl(z,1), z2 = __shfl(z,2), z3 = __shfl(z,3), z4 = __shfl(z,4);
    if (lane == 0){
      skey[0]=a0; skey[1]=a1; skey[2]=c0; skey[3]=c1; skey[4]=d0; skey[5]=d1;
      float best = z0; int arg = 0;
      if (z1 > best){ best = z1; arg = 1; }
      if (z2 > best){ best = z2; arg = 2; }
      if (z3 > best){ best = z3; arg = 3; }
      if (z4 > best){ best = z4; arg = 4; }
      skmax = arg;
    }
  }
  // ballot group table: row i has ceil(i/64) 64-wide groups; entry = (i<<2)|jw
  if (tid >= 1 && tid < 256){
    int i = tid;
    int q = (i - 1) >> 6, m = (i - 1) & 63;
    int base = 32*q*(q+1) + m*(q+1);
    int ng = q + 1;
    for (int jw = 0; jw < ng; ++jw) ctab[base + jw] = (unsigned short)((i << 2) | jw);
  }
  for (int idx = tid; idx < HH*HH; idx += 512){
    int k = idx >> 5, m = idx & 31;
    wd1T[m*40 + k] = f2bf(Wd1[idx]);
    int f = m;
    wd2T[f*40 + k] = (f < FF) ? f2bf(Wd2[k*FF + f]) : 0;
  }
  if (tid < HH) bd1s[tid] = bd1[tid];
  if (tid < HH) bd2p[tid] = (tid < FF) ? bd2[tid] : 0.f;
  if (tid < 16){
    short4v t;
    #pragma unroll
    for (int b = 0; b < 4; ++b) t[b] = (short)(((tid >> b) & 1) * 0x3F80);
    tab16[tid] = t;
  }
  for (int idx = tid; idx < NN*9; idx += 512) Abits[idx] = 0u;
  __syncthreads();

  // ---- phase 1: sample_Z = Z_mu + std*normal (Box-Muller, fast hash) -> zT ----
  {
    uint32_t k0 = skey[0], k1 = skey[1];
    const float* zp = outro + O_ZMU + g*NN*HH;
    float zmu[16]; uint32_t bits[16];
    #pragma unroll
    for (int p = 0; p < 16; ++p){
      int idx = p*512 + tid;
      zmu[p] = zp[idx];                              // coalesced
      bits[p] = mmhash((uint32_t)(g*NN*HH + idx), k0, k1);
    }
    #pragma unroll
    for (int p = 0; p < 8; ++p){
      float u1 = 1.0f - u01(bits[p]);                // (0,1]
      float u2 = u01(bits[p + 8]);                   // [0,1) revolutions
      float r  = sqrtf(-1.3862944f * __builtin_amdgcn_logf(u1));  // sqrt(-2 ln u1)
      float nA = r * __builtin_amdgcn_cosf(u2);
      float nB = r * __builtin_amdgcn_sinf(u2);
      int ia = p*512 + tid, ib = (p + 8)*512 + tid;
      zT[ia & 31][ia >> 5] = f2bf(zmu[p]     + 0.22313016f * nA);
      zT[ib & 31][ib >> 5] = f2bf(zmu[p + 8] + 0.22313016f * nB);
    }
  }

  // ---- phase 2a: ballot-built strict-lower adjacency rows (fast hash) ----
  {
    uint32_t k4 = skey[4], k5 = skey[5];
    const int* tintp = (const int*)ws + W_LT + ((size_t)skmax*GG + g)*NN*NN;
    uint32_t ebase = (uint32_t)(g*NN*NN);
    for (int c = wvid*2; c < 636; c += 16){
      uint32_t w = *(const uint32_t*)&ctab[c];       // entries c, c+1
      int ea = (int)(w & 0xFFFFu), eb = (int)(w >> 16);
      int ia = ea >> 2, ja = ea & 3, ib = eb >> 2, jb = eb & 3;
      int j0a = ja*64 + lane, j0b = jb*64 + lane;
      int ta = tintp[ia*NN + j0a];
      int tb = tintp[ib*NN + j0b];
      uint32_t ha = mmhash(ebase + (uint32_t)(ia*NN + j0a), k4, k5);
      uint32_t hb = mmhash(ebase + (uint32_t)(ib*NN + j0b), k4, k5);
      unsigned long long ma = __ballot((j0a < ia) && ((int)(ha >> 9) > ta));
      unsigned long long mb = __ballot((j0b < ib) && ((int)(hb >> 9) > tb));
      if (lane == 0){ Abits[ia*9 + 2*ja] = (uint32_t)ma; Abits[ib*9 + 2*jb] = (uint32_t)mb; }
      if (lane == 1){ Abits[ia*9 + 2*ja + 1] = (uint32_t)(ma >> 32); Abits[ib*9 + 2*jb + 1] = (uint32_t)(mb >> 32); }
    }
  }
  __syncthreads();

  // ---- phase 2b: A = L | L^T via 32x32 shuffle bit-transpose ----
  {
    int l31 = lane & 31, half = lane >> 5;
    uint32_t tw[4];
    const uint32_t msk[5] = {0xFFFF0000u, 0xFF00FF00u, 0xF0F0F0F0u, 0xCCCCCCCCu, 0xAAAAAAAAu};
    #pragma unroll
    for (int p = 0; p < 4; ++p){
      int t = wvid*8 + p*2 + half;       // tile 0..63
      int I = t >> 3, J = t & 7;
      uint32_t x = Abits[(I*32 + l31)*9 + J];
      #pragma unroll
      for (int s = 0; s < 5; ++s){
        int k = 16 >> s;
        uint32_t mh = msk[s];
        uint32_t y = __shfl_xor(x, k, 64);
        x = (lane & k) ? ((x & mh) | ((y >> k) & ~mh))
                       : ((x & ~mh) | ((y << k) & mh));
      }
      tw[p] = x;
    }
    __syncthreads();
    #pragma unroll
    for (int p = 0; p < 4; ++p){
      int t = wvid*8 + p*2 + half;
      int I = t >> 3, J = t & 7;
      Abits[(J*32 + l31)*9 + I] |= tw[p];
    }
  }
  __syncthreads();

  // ---- phase 3: AZ = A @ Zs via MFMA -> azb (bf16) ----
  #pragma unroll
  for (int rr = 0; rr < 2; ++rr){
    int rt = wvid*2 + rr;
    int row = rt*16 + l15;
    float4v acc0 = {0.f,0.f,0.f,0.f}, acc1 = {0.f,0.f,0.f,0.f};
    #pragma unroll
    for (int c = 0; c < 8; ++c){
      uint32_t byte = (Abits[row*9 + c] >> (l4*8)) & 0xFFu;
      short4v lo = tab16[byte & 15u];
      short4v hi = tab16[byte >> 4];
      short8v af = {lo[0],lo[1],lo[2],lo[3],hi[0],hi[1],hi[2],hi[3]};
      short8v b0 = *(const short8v*)&zT[l15][c*32 + l4*8];
      short8v b1 = *(const short8v*)&zT[16 + l15][c*32 + l4*8];
      acc0 = __builtin_amdgcn_mfma_f32_16x16x32_bf16(af, b0, acc0, 0, 0, 0);
      acc1 = __builtin_amdgcn_mfma_f32_16x16x32_bf16(af, b1, acc1, 0, 0, 0);
    }
    #pragma unroll
    for (int r2 = 0; r2 < 4; ++r2){
      azb[rt*16 + l4*4 + r2][l15]      = f2bf(acc0[r2]);
      azb[rt*16 + l4*4 + r2][16 + l15] = f2bf(acc1[r2]);
    }
  }
  __syncthreads();

  // ---- phase 4: h^T = relu(AZ @ Wd1 + bd1)^T via MFMA -> zT ----
  {
    short8v bf0 = *(const short8v*)&wd1T[l15*40 + l4*8];
    short8v bf1 = *(const short8v*)&wd1T[(16 + l15)*40 + l4*8];
    float bb0 = bd1s[l15], bb1 = bd1s[16 + l15];
    #pragma unroll
    for (int mt = 0; mt < 2; ++mt){
      int n0 = wvid*32 + mt*16;
      short8v af = *(const short8v*)&azb[n0 + l15][l4*8];
      float4v c0 = {bb0, bb0, bb0, bb0};
      float4v c1 = {bb1, bb1, bb1, bb1};
      c0 = __builtin_amdgcn_mfma_f32_16x16x32_bf16(af, bf0, c0, 0, 0, 0);
      c1 = __builtin_amdgcn_mfma_f32_16x16x32_bf16(af, bf1, c1, 0, 0, 0);
      int nb = n0 + l4*4;
      short4v p0, p1;
      #pragma unroll
      for (int r2 = 0; r2 < 4; ++r2){
        p0[r2] = (short)f2bf(fmaxf(c0[r2], 0.f));
        p1[r2] = (short)f2bf(fmaxf(c1[r2], 0.f));
      }
      *(short4v*)&zT[l15][nb] = p0;
      *(short4v*)&zT[16 + l15][nb] = p1;
    }
  }
  __syncthreads();

  // ---- phase 5: Ah = A @ h via MFMA -> azb (bf16) ----
  #pragma unroll
  for (int rr = 0; rr < 2; ++rr){
    int rt = wvid*2 + rr;
    int row = rt*16 + l15;
    float4v acc0 = {0.f,0.f,0.f,0.f}, acc1 = {0.f,0.f,0.f,0.f};
    #pragma unroll
    for (int c = 0; c < 8; ++c){
      uint32_t byte = (Abits[row*9 + c] >> (l4*8)) & 0xFFu;
      short4v lo = tab16[byte & 15u];
      short4v hi = tab16[byte >> 4];
      short8v af = {lo[0],lo[1],lo[2],lo[3],hi[0],hi[1],hi[2],hi[3]};
      short8v b0 = *(const short8v*)&zT[l15][c*32 + l4*8];
      short8v b1 = *(const short8v*)&zT[16 + l15][c*32 + l4*8];
      acc0 = __builtin_amdgcn_mfma_f32_16x16x32_bf16(af, b0, acc0, 0, 0, 0);
      acc1 = __builtin_amdgcn_mfma_f32_16x16x32_bf16(af, b1, acc1, 0, 0, 0);
    }
    #pragma unroll
    for (int r2 = 0; r2 < 4; ++r2){
      azb[rt*16 + l4*4 + r2][l15]      = f2bf(acc0[r2]);
      azb[rt*16 + l4*4 + r2][16 + l15] = f2bf(acc1[r2]);
    }
  }
  __syncthreads();

  // ---- phase 6: Xmu = Ah @ Wd2 + bd2 via MFMA ; squared error ; reduce ----
  float part = 0.f;
  {
    short8v bf0 = *(const short8v*)&wd2T[l15*40 + l4*8];
    short8v bf1 = *(const short8v*)&wd2T[(16 + l15)*40 + l4*8];
    float bb0 = bd2p[l15], bb1 = bd2p[16 + l15];
    #pragma unroll
    for (int mt = 0; mt < 2; ++mt){
      int n0 = wvid*32 + mt*16;
      short8v af = *(const short8v*)&azb[n0 + l15][l4*8];
      float4v c0 = {bb0, bb0, bb0, bb0};
      float4v c1 = {bb1, bb1, bb1, bb1};
      c0 = __builtin_amdgcn_mfma_f32_16x16x32_bf16(af, bf0, c0, 0, 0, 0);
      c1 = __builtin_amdgcn_mfma_f32_16x16x32_bf16(af, bf1, c1, 0, 0, 0);
      int nb = n0 + l4*4;
      #pragma unroll
      for (int r2 = 0; r2 < 4; ++r2){
        int n = nb + r2;
        float d0 = c0[r2] - X[((size_t)g*NN + n)*FF + l15];
        part = fmaf(d0, d0, part);
        if (l15 < FF - 16){
          float d1 = c1[r2] - X[((size_t)g*NN + n)*FF + 16 + l15];
          part = fmaf(d1, d1, part);
        }
      }
    }
  }
  // wave-level shuffle reduce, then single cross-wave pass
  #pragma unroll
  for (int off = 32; off > 0; off >>= 1) part += __shfl_down(part, off);
  if (lane == 0) wsum[wvid] = part;
  __syncthreads();
  if (tid == 0){
    float s = 0.f;
    #pragma unroll
    for (int wq = 0; wq < 8; ++wq) s += wsum[wq];
    ws[W_PART + it*GG + g] = s;
  }
}

// ---------- K5: final loss reduction ----------
__global__ void k_final(float* __restrict__ out, const float* __restrict__ ws){
  int tid = threadIdx.x;
  double s = 0.0;
  for (int i = tid; i < NS*GG; i += 512) s += (double)ws[W_PART + i];
  __shared__ double rd[512];
  rd[tid] = s;
  __syncthreads();
  for (int st = 256; st > 0; st >>= 1){
    if (tid < st) rd[tid] += rd[tid + st];
    __syncthreads();
  }
  if (tid == 0) out[O_LOSS] = (float)(rd[0] * (0.5/6400.0));
}

extern "C" void kernel_launch(void* const* d_in, const int* in_sizes, int n_in,
                              void* d_out, int out_size, void* d_ws, size_t ws_size,
                              hipStream_t stream){
  const float* X   = (const float*)d_in[0];
  const float* Wz1 = (const float*)d_in[1];
  const float* bz1 = (const float*)d_in[2];
  const float* Wz2 = (const float*)d_in[3];
  const float* bz2 = (const float*)d_in[4];
  const float* Wa1 = (const float*)d_in[5];
  const float* ba1 = (const float*)d_in[6];
  const float* Wth = (const float*)d_in[7];
  const float* Wal = (const float*)d_in[8];
  const float* bal = (const float*)d_in[9];
  const float* Wd1 = (const float*)d_in[10];
  const float* bd1 = (const float*)d_in[11];
  const float* Wd2 = (const float*)d_in[12];
  const float* bd2 = (const float*)d_in[13];
  const int* seed  = (const int*)d_in[14];
  float* out = (float*)d_out;
  float* ws  = (float*)d_ws;

  hipLaunchKernelGGL(k_encode, dim3(32,64), dim3(256), 0, stream,
                     X, Wz1, bz1, Wz2, bz2, Wa1, ba1, out, ws);
  hipLaunchKernelGGL(k_alpha, dim3(64), dim3(256), 0, stream, Wal, bal, out, ws);
  hipLaunchKernelGGL(k_theta, dim3(16,16,64), dim3(256), 0, stream, Wth, out, ws);
  hipLaunchKernelGGL(k_loop, dim3(64,100), dim3(512), 0, stream,
                     Wd1, bd1, Wd2, bd2, X, seed, out, ws);
  hipLaunchKernelGGL(k_final, dim3(1), dim3(512), 0, stream, out, ws);
}

// Round 6
// 572.534 us; speedup vs baseline: 3.5747x; 2.2573x over previous
//
#include <hip/hip_runtime.h>
#include <stdint.h>

#define GG 64
#define NN 256
#define FF 20
#define HH 32
#define KK 5
#define NS 100

// out offsets (floats)
#define O_PT   0
#define O_LA   20971520
#define O_ZMU  20971840
#define O_LOSS 21496128

// ws offsets (floats)
#define W_HA   0
#define W_LT   524288          /* u16 [K][G][N][N] threshold on top-16 hash bits */
#define W_PART 21495808        /* [NS*G] */

typedef __attribute__((ext_vector_type(8))) short short8v;
typedef __attribute__((ext_vector_type(4))) short short4v;
typedef __attribute__((ext_vector_type(4))) float float4v;

__device__ __forceinline__ uint32_t rotl32(uint32_t v, int n){ return (v << n) | (v >> (32 - n)); }

// JAX threefry2x32 (20 rounds) — used only for key derivation + gumbel (bit-exact)
__device__ __forceinline__ void tf2x32(uint32_t k0, uint32_t k1, uint32_t x0, uint32_t x1,
                                       uint32_t& o0, uint32_t& o1){
  uint32_t k2 = k0 ^ k1 ^ 0x1BD11BDAu;
  x0 += k0; x1 += k1;
  x0 += x1; x1 = rotl32(x1,13); x1 ^= x0;
  x0 += x1; x1 = rotl32(x1,15); x1 ^= x0;
  x0 += x1; x1 = rotl32(x1,26); x1 ^= x0;
  x0 += x1; x1 = rotl32(x1, 6); x1 ^= x0;
  x0 += k1; x1 += k2 + 1u;
  x0 += x1; x1 = rotl32(x1,17); x1 ^= x0;
  x0 += x1; x1 = rotl32(x1,29); x1 ^= x0;
  x0 += x1; x1 = rotl32(x1,16); x1 ^= x0;
  x0 += x1; x1 = rotl32(x1,24); x1 ^= x0;
  x0 += k2; x1 += k0 + 2u;
  x0 += x1; x1 = rotl32(x1,13); x1 ^= x0;
  x0 += x1; x1 = rotl32(x1,15); x1 ^= x0;
  x0 += x1; x1 = rotl32(x1,26); x1 ^= x0;
  x0 += x1; x1 = rotl32(x1, 6); x1 ^= x0;
  x0 += k0; x1 += k1 + 3u;
  x0 += x1; x1 = rotl32(x1,17); x1 ^= x0;
  x0 += x1; x1 = rotl32(x1,29); x1 ^= x0;
  x0 += x1; x1 = rotl32(x1,16); x1 ^= x0;
  x0 += x1; x1 = rotl32(x1,24); x1 ^= x0;
  x0 += k1; x1 += k2 + 4u;
  x0 += x1; x1 = rotl32(x1,13); x1 ^= x0;
  x0 += x1; x1 = rotl32(x1,15); x1 ^= x0;
  x0 += x1; x1 = rotl32(x1,26); x1 ^= x0;
  x0 += x1; x1 = rotl32(x1, 6); x1 ^= x0;
  o0 = x0 + k2; o1 = x1 + k0 + 5u;
}

// fast counter hash: double murmur3 finalizer, salted with JAX-derived keys.
__device__ __forceinline__ uint32_t mmhash(uint32_t e, uint32_t ka, uint32_t kb){
  uint32_t x = e + ka;
  x ^= x >> 16; x *= 0x85EBCA6Bu; x ^= x >> 13; x *= 0xC2B2AE35u; x ^= x >> 16;
  x ^= kb;
  x ^= x >> 16; x *= 0x85EBCA6Bu; x ^= x >> 13; x *= 0xC2B2AE35u; x ^= x >> 16;
  return x;
}

__device__ __forceinline__ float u01(uint32_t b){
  return __uint_as_float((b >> 9) | 0x3f800000u) - 1.0f;
}

__device__ __forceinline__ unsigned short f2bf(float f){
  uint32_t u = __float_as_uint(f);
  uint32_t r = u + 0x7FFFu + ((u >> 16) & 1u);
  return (unsigned short)(r >> 16);
}

// ---------- K1: per-node encoders: Z_mu -> out, ha -> ws ----------
__global__ void k_encode(const float* __restrict__ X,
                         const float* __restrict__ Wz1, const float* __restrict__ bz1,
                         const float* __restrict__ Wz2, const float* __restrict__ bz2,
                         const float* __restrict__ Wa1, const float* __restrict__ ba1,
                         float* __restrict__ out, float* __restrict__ ws){
  int g = blockIdx.y, nt = blockIdx.x;   // nt 0..31 (8 nodes each)
  int tid = threadIdx.x;
  int nl = tid >> 5, h = tid & 31;
  __shared__ float xrow[8][FF];
  __shared__ float hzrow[8][HH];
  if (tid < 8*FF){
    int a = tid / FF, b = tid % FF;
    xrow[a][b] = X[(g*NN + nt*8 + a)*FF + b];
  }
  __syncthreads();
  float hz = bz1[h], ha = ba1[h];
  for (int f = 0; f < FF; ++f){
    float xv = xrow[nl][f];
    hz = fmaf(xv, Wz1[f*HH + h], hz);
    ha = fmaf(xv, Wa1[f*HH + h], ha);
  }
  hz = fmaxf(hz, 0.f); ha = fmaxf(ha, 0.f);
  hzrow[nl][h] = hz;
  int n = nt*8 + nl;
  ws[W_HA + (g*NN + n)*HH + h] = ha;
  __syncthreads();
  float zm = bz2[h];
  for (int hh = 0; hh < HH; ++hh)
    zm = fmaf(hzrow[nl][hh], Wz2[hh*HH + h], zm);
  out[O_ZMU + (g*NN + n)*HH + h] = zm;
}

// ---------- K2: logit_alpha = mean_n(ha) @ Walpha + balpha ----------
__global__ void k_alpha(const float* __restrict__ Walpha, const float* __restrict__ balpha,
                        float* __restrict__ out, const float* __restrict__ ws){
  int g = blockIdx.x; int tid = threadIdx.x;
  int h = tid & 31, p = tid >> 5;  // p 0..7
  __shared__ float sums[8][HH];
  __shared__ float meanh[HH];
  float s = 0.f;
  for (int n = p; n < NN; n += 8) s += ws[W_HA + (g*NN + n)*HH + h];
  sums[p][h] = s;
  __syncthreads();
  if (p == 0){
    float t = 0.f;
    for (int q = 0; q < 8; ++q) t += sums[q][h];
    meanh[h] = t * (1.0f/256.0f);
  }
  __syncthreads();
  if (tid < KK){
    float la = balpha[tid];
    for (int hh = 0; hh < HH; ++hh) la = fmaf(meanh[hh], Walpha[hh*KK + tid], la);
    out[O_LA + g*KK + tid] = la;
  }
}

// ---------- K3: prob_theta (out) + u16 threshold (ws, k-major) ----------
// Re-tiled: block = (g, 8 i, 32 j). Results staged in LDS, then written in a
// dense burst of fully-covered 64B lines (kills write-allocate RMW traffic).
__global__ __launch_bounds__(256)
void k_theta(const float* __restrict__ Wtheta,
             float* __restrict__ out, float* __restrict__ ws){
  int jt = blockIdx.x;   // 0..7   j0 = jt*32
  int it = blockIdx.y;   // 0..31  i0 = it*8
  int g  = blockIdx.z;
  int tid = threadIdx.x;

  __shared__ float wth[HH*HH*KK];       // 20 KB [h][f*K+k]
  __shared__ float hai[8][HH];          // 1 KB
  __shared__ float haj[32][HH + 1];     // 4.1 KB (pad kills 32-way conflict)
  __shared__ float tloc[8][HH*KK];      // 5 KB [i][f*K+k]
  __shared__ float sOut[8*32*KK];       // 5 KB  flat [i][j*5+k]
  __shared__ unsigned short sT[KK][8][32]; // 2.5 KB

  for (int idx = tid; idx < HH*HH*KK; idx += 256) wth[idx] = Wtheta[idx];
  {
    int r = tid >> 5, c = tid & 31;
    hai[r][c] = ws[W_HA + (g*NN + it*8 + r)*HH + c];
  }
  for (int idx = tid; idx < 32*HH; idx += 256){
    int r = idx >> 5, c = idx & 31;
    haj[r][c] = ws[W_HA + (g*NN + jt*32 + r)*HH + c];
  }
  __syncthreads();
  for (int idx = tid; idx < 8*HH*KK; idx += 256){
    int i = idx / (HH*KK), rem = idx % (HH*KK);
    float a = 0.f;
    for (int hh = 0; hh < HH; ++hh) a = fmaf(hai[i][hh], wth[hh*(HH*KK) + rem], a);
    tloc[i][rem] = a;
  }
  __syncthreads();

  int il = tid >> 5, jl = tid & 31;
  float acc[KK] = {0,0,0,0,0};
  for (int f = 0; f < HH; ++f){
    float hv = haj[jl][f];
    #pragma unroll
    for (int k = 0; k < KK; ++k) acc[k] = fmaf(tloc[il][f*KK+k], hv, acc[k]);
  }
  int i = it*8 + il, j = jt*32 + jl;
  #pragma unroll
  for (int k = 0; k < KK; ++k){
    float v = acc[k];
    float s = 1.f / (1.f + expf(-v));
    sOut[(il*32 + jl)*KK + k] = (i == j) ? 0.f : s;
    float thrf = 1.f - s;                            // sigmoid(-v)
    float fthr = (thrf - 1e-6f) * (1.f / (1.f - 2e-6f));
    int t = (int)floorf(fthr * 65536.f);
    t = t < 0 ? 0 : (t > 65535 ? 65535 : t);
    sT[k][il][jl] = (unsigned short)t;
  }
  __syncthreads();

  // out burst: 1280 dwords as 5 rounds x 256 consecutive dwords
  #pragma unroll
  for (int r = 0; r < 5; ++r){
    int f = r*256 + tid;
    int i2 = f / (32*KK), rem = f % (32*KK);
    out[O_PT + ((size_t)(g*NN + it*8 + i2)*NN + jt*32)*KK + rem] = sOut[f];
  }
  // tint burst: u16, 32 lanes x 2B = full 64B lines
  unsigned short* tp = (unsigned short*)(ws + W_LT);
  {
    int r2 = tid >> 5, c2 = tid & 31;
    #pragma unroll
    for (int k = 0; k < KK; ++k)
      tp[((size_t)k*GG + g)*NN*NN + (it*8 + r2)*NN + jt*32 + c2] = sT[k][r2][c2];
  }
}

// ---------- K4: the whole MC loop, one block per (it, g) ----------
__global__ __launch_bounds__(512, 6)
void k_loop(const float* __restrict__ Wd1, const float* __restrict__ bd1,
            const float* __restrict__ Wd2, const float* __restrict__ bd2,
            const float* __restrict__ X, const int* __restrict__ seedp,
            const float* __restrict__ outro, float* __restrict__ ws){
  int g  = blockIdx.x;   // 0..63
  int it = blockIdx.y;   // 0..99
  int tid = threadIdx.x; // 0..511
  int lane = tid & 63, wvid = tid >> 6;
  int l15 = lane & 15, l4 = lane >> 4;

  __shared__ unsigned short zT[HH][264];   // bf16 Z^T then h^T        16.9KB
  __shared__ unsigned short azb[NN][40];   // bf16 AZ then Ah           20.5KB
  __shared__ uint32_t Abits[NN*9];         // adjacency bits, 9 w/row   9.2KB
  __shared__ unsigned short wd1T[HH*40];   // Wd1^T bf16 [m][k]         2.5KB
  __shared__ unsigned short wd2T[HH*40];   // Wd2^T bf16 padded [f][k]  2.5KB
  __shared__ unsigned short ctab[636];     // ballot group table        1.27KB
  __shared__ float bd1s[HH], bd2p[HH];
  __shared__ short4v tab16[16];            // nibble -> 4 bf16 0/1      128B
  __shared__ float wsum[8];
  __shared__ uint32_t skey[6];
  __shared__ int skmax;

  // wave 0: derive keys (bit-exact threefry) + parallel gumbel argmax
  if (wvid == 0){
    uint32_t seed = (uint32_t)(*seedp);
    uint32_t b0, b1, a0, a1, c0, c1, d0, d1;
    tf2x32(0u, seed, 0u, (uint32_t)it, b0, b1);  // fold_in(base, it)
    tf2x32(b0, b1, 0u, 0u, a0, a1);              // split -> k1
    tf2x32(b0, b1, 0u, 1u, c0, c1);              // k2
    tf2x32(b0, b1, 0u, 2u, d0, d1);              // k3
    float z = -3.4e38f;
    if (lane < KK){
      uint32_t e = (uint32_t)(g*KK + lane), r0, r1;
      tf2x32(c0, c1, 0u, e, r0, r1);
      float f = u01(r0 ^ r1);
      float u = fmaxf(1.17549435e-38f, f + 1.17549435e-38f);
      float gum = -logf(-logf(u));
      z = outro[O_LA + g*KK + lane] + gum;
    }
    float z0 = __shfl(z,0), z1 = __shfl(z,1), z2 = __shfl(z,2), z3 = __shfl(z,3), z4 = __shfl(z,4);
    if (lane == 0){
      skey[0]=a0; skey[1]=a1; skey[2]=c0; skey[3]=c1; skey[4]=d0; skey[5]=d1;
      float best = z0; int arg = 0;
      if (z1 > best){ best = z1; arg = 1; }
      if (z2 > best){ best = z2; arg = 2; }
      if (z3 > best){ best = z3; arg = 3; }
      if (z4 > best){ best = z4; arg = 4; }
      skmax = arg;
    }
  }
  // ballot group table: row i has ceil(i/64) 64-wide groups; entry = (i<<2)|jw
  if (tid >= 1 && tid < 256){
    int i = tid;
    int q = (i - 1) >> 6, m = (i - 1) & 63;
    int base = 32*q*(q+1) + m*(q+1);
    int ng = q + 1;
    for (int jw = 0; jw < ng; ++jw) ctab[base + jw] = (unsigned short)((i << 2) | jw);
  }
  for (int idx = tid; idx < HH*HH; idx += 512){
    int k = idx >> 5, m = idx & 31;
    wd1T[m*40 + k] = f2bf(Wd1[idx]);
    int f = m;
    wd2T[f*40 + k] = (f < FF) ? f2bf(Wd2[k*FF + f]) : 0;
  }
  if (tid < HH) bd1s[tid] = bd1[tid];
  if (tid < HH) bd2p[tid] = (tid < FF) ? bd2[tid] : 0.f;
  if (tid < 16){
    short4v t;
    #pragma unroll
    for (int b = 0; b < 4; ++b) t[b] = (short)(((tid >> b) & 1) * 0x3F80);
    tab16[tid] = t;
  }
  for (int idx = tid; idx < NN*9; idx += 512) Abits[idx] = 0u;
  __syncthreads();

  // ---- phase 1: sample_Z = Z_mu + std*normal (Box-Muller, fast hash) -> zT ----
  {
    uint32_t k0 = skey[0], k1 = skey[1];
    const float* zp = outro + O_ZMU + g*NN*HH;
    float zmu[16]; uint32_t bits[16];
    #pragma unroll
    for (int p = 0; p < 16; ++p){
      int idx = p*512 + tid;
      zmu[p] = zp[idx];                              // coalesced
      bits[p] = mmhash((uint32_t)(g*NN*HH + idx), k0, k1);
    }
    #pragma unroll
    for (int p = 0; p < 8; ++p){
      float u1 = 1.0f - u01(bits[p]);                // (0,1]
      float u2 = u01(bits[p + 8]);                   // [0,1) revolutions
      float r  = sqrtf(-1.3862944f * __builtin_amdgcn_logf(u1));  // sqrt(-2 ln u1)
      float nA = r * __builtin_amdgcn_cosf(u2);
      float nB = r * __builtin_amdgcn_sinf(u2);
      int ia = p*512 + tid, ib = (p + 8)*512 + tid;
      zT[ia & 31][ia >> 5] = f2bf(zmu[p]     + 0.22313016f * nA);
      zT[ib & 31][ib >> 5] = f2bf(zmu[p + 8] + 0.22313016f * nB);
    }
  }

  // ---- phase 2a: ballot-built strict-lower adjacency rows (fast hash, u16 thr) ----
  {
    uint32_t k4 = skey[4], k5 = skey[5];
    const unsigned short* tintp = (const unsigned short*)(ws + W_LT)
                                  + ((size_t)skmax*GG + g)*NN*NN;
    uint32_t ebase = (uint32_t)(g*NN*NN);
    for (int c = wvid*2; c < 636; c += 16){
      uint32_t w = *(const uint32_t*)&ctab[c];       // entries c, c+1
      int ea = (int)(w & 0xFFFFu), eb = (int)(w >> 16);
      int ia = ea >> 2, ja = ea & 3, ib = eb >> 2, jb = eb & 3;
      int j0a = ja*64 + lane, j0b = jb*64 + lane;
      uint32_t ta = tintp[ia*NN + j0a];
      uint32_t tb = tintp[ib*NN + j0b];
      uint32_t ha = mmhash(ebase + (uint32_t)(ia*NN + j0a), k4, k5);
      uint32_t hb = mmhash(ebase + (uint32_t)(ib*NN + j0b), k4, k5);
      unsigned long long ma = __ballot((j0a < ia) && ((ha >> 16) > ta));
      unsigned long long mb = __ballot((j0b < ib) && ((hb >> 16) > tb));
      if (lane == 0){ Abits[ia*9 + 2*ja] = (uint32_t)ma; Abits[ib*9 + 2*jb] = (uint32_t)mb; }
      if (lane == 1){ Abits[ia*9 + 2*ja + 1] = (uint32_t)(ma >> 32); Abits[ib*9 + 2*jb + 1] = (uint32_t)(mb >> 32); }
    }
  }
  __syncthreads();

  // ---- phase 2b: A = L | L^T via 32x32 shuffle bit-transpose ----
  {
    int l31 = lane & 31, half = lane >> 5;
    uint32_t tw[4];
    const uint32_t msk[5] = {0xFFFF0000u, 0xFF00FF00u, 0xF0F0F0F0u, 0xCCCCCCCCu, 0xAAAAAAAAu};
    #pragma unroll
    for (int p = 0; p < 4; ++p){
      int t = wvid*8 + p*2 + half;       // tile 0..63
      int I = t >> 3, J = t & 7;
      uint32_t x = Abits[(I*32 + l31)*9 + J];
      #pragma unroll
      for (int s = 0; s < 5; ++s){
        int k = 16 >> s;
        uint32_t mh = msk[s];
        uint32_t y = __shfl_xor(x, k, 64);
        x = (lane & k) ? ((x & mh) | ((y >> k) & ~mh))
                       : ((x & ~mh) | ((y << k) & mh));
      }
      tw[p] = x;
    }
    __syncthreads();
    #pragma unroll
    for (int p = 0; p < 4; ++p){
      int t = wvid*8 + p*2 + half;
      int I = t >> 3, J = t & 7;
      Abits[(J*32 + l31)*9 + I] |= tw[p];
    }
  }
  __syncthreads();

  // ---- phase 3: AZ = A @ Zs via MFMA -> azb (bf16) ----
  #pragma unroll
  for (int rr = 0; rr < 2; ++rr){
    int rt = wvid*2 + rr;
    int row = rt*16 + l15;
    float4v acc0 = {0.f,0.f,0.f,0.f}, acc1 = {0.f,0.f,0.f,0.f};
    #pragma unroll
    for (int c = 0; c < 8; ++c){
      uint32_t byte = (Abits[row*9 + c] >> (l4*8)) & 0xFFu;
      short4v lo = tab16[byte & 15u];
      short4v hi = tab16[byte >> 4];
      short8v af = {lo[0],lo[1],lo[2],lo[3],hi[0],hi[1],hi[2],hi[3]};
      short8v b0 = *(const short8v*)&zT[l15][c*32 + l4*8];
      short8v b1 = *(const short8v*)&zT[16 + l15][c*32 + l4*8];
      acc0 = __builtin_amdgcn_mfma_f32_16x16x32_bf16(af, b0, acc0, 0, 0, 0);
      acc1 = __builtin_amdgcn_mfma_f32_16x16x32_bf16(af, b1, acc1, 0, 0, 0);
    }
    #pragma unroll
    for (int r2 = 0; r2 < 4; ++r2){
      azb[rt*16 + l4*4 + r2][l15]      = f2bf(acc0[r2]);
      azb[rt*16 + l4*4 + r2][16 + l15] = f2bf(acc1[r2]);
    }
  }
  __syncthreads();

  // ---- phase 4: h^T = relu(AZ @ Wd1 + bd1)^T via MFMA -> zT ----
  {
    short8v bf0 = *(const short8v*)&wd1T[l15*40 + l4*8];
    short8v bf1 = *(const short8v*)&wd1T[(16 + l15)*40 + l4*8];
    float bb0 = bd1s[l15], bb1 = bd1s[16 + l15];
    #pragma unroll
    for (int mt = 0; mt < 2; ++mt){
      int n0 = wvid*32 + mt*16;
      short8v af = *(const short8v*)&azb[n0 + l15][l4*8];
      float4v c0 = {bb0, bb0, bb0, bb0};
      float4v c1 = {bb1, bb1, bb1, bb1};
      c0 = __builtin_amdgcn_mfma_f32_16x16x32_bf16(af, bf0, c0, 0, 0, 0);
      c1 = __builtin_amdgcn_mfma_f32_16x16x32_bf16(af, bf1, c1, 0, 0, 0);
      int nb = n0 + l4*4;
      short4v p0, p1;
      #pragma unroll
      for (int r2 = 0; r2 < 4; ++r2){
        p0[r2] = (short)f2bf(fmaxf(c0[r2], 0.f));
        p1[r2] = (short)f2bf(fmaxf(c1[r2], 0.f));
      }
      *(short4v*)&zT[l15][nb] = p0;
      *(short4v*)&zT[16 + l15][nb] = p1;
    }
  }
  __syncthreads();

  // ---- phase 5: Ah = A @ h via MFMA -> azb (bf16) ----
  #pragma unroll
  for (int rr = 0; rr < 2; ++rr){
    int rt = wvid*2 + rr;
    int row = rt*16 + l15;
    float4v acc0 = {0.f,0.f,0.f,0.f}, acc1 = {0.f,0.f,0.f,0.f};
    #pragma unroll
    for (int c = 0; c < 8; ++c){
      uint32_t byte = (Abits[row*9 + c] >> (l4*8)) & 0xFFu;
      short4v lo = tab16[byte & 15u];
      short4v hi = tab16[byte >> 4];
      short8v af = {lo[0],lo[1],lo[2],lo[3],hi[0],hi[1],hi[2],hi[3]};
      short8v b0 = *(const short8v*)&zT[l15][c*32 + l4*8];
      short8v b1 = *(const short8v*)&zT[16 + l15][c*32 + l4*8];
      acc0 = __builtin_amdgcn_mfma_f32_16x16x32_bf16(af, b0, acc0, 0, 0, 0);
      acc1 = __builtin_amdgcn_mfma_f32_16x16x32_bf16(af, b1, acc1, 0, 0, 0);
    }
    #pragma unroll
    for (int r2 = 0; r2 < 4; ++r2){
      azb[rt*16 + l4*4 + r2][l15]      = f2bf(acc0[r2]);
      azb[rt*16 + l4*4 + r2][16 + l15] = f2bf(acc1[r2]);
    }
  }
  __syncthreads();

  // ---- phase 6: Xmu = Ah @ Wd2 + bd2 via MFMA ; squared error ; reduce ----
  float part = 0.f;
  {
    short8v bf0 = *(const short8v*)&wd2T[l15*40 + l4*8];
    short8v bf1 = *(const short8v*)&wd2T[(16 + l15)*40 + l4*8];
    float bb0 = bd2p[l15], bb1 = bd2p[16 + l15];
    #pragma unroll
    for (int mt = 0; mt < 2; ++mt){
      int n0 = wvid*32 + mt*16;
      short8v af = *(const short8v*)&azb[n0 + l15][l4*8];
      float4v c0 = {bb0, bb0, bb0, bb0};
      float4v c1 = {bb1, bb1, bb1, bb1};
      c0 = __builtin_amdgcn_mfma_f32_16x16x32_bf16(af, bf0, c0, 0, 0, 0);
      c1 = __builtin_amdgcn_mfma_f32_16x16x32_bf16(af, bf1, c1, 0, 0, 0);
      int nb = n0 + l4*4;
      #pragma unroll
      for (int r2 = 0; r2 < 4; ++r2){
        int n = nb + r2;
        float d0 = c0[r2] - X[((size_t)g*NN + n)*FF + l15];
        part = fmaf(d0, d0, part);
        if (l15 < FF - 16){
          float d1 = c1[r2] - X[((size_t)g*NN + n)*FF + 16 + l15];
          part = fmaf(d1, d1, part);
        }
      }
    }
  }
  // wave-level shuffle reduce, then single cross-wave pass
  #pragma unroll
  for (int off = 32; off > 0; off >>= 1) part += __shfl_down(part, off);
  if (lane == 0) wsum[wvid] = part;
  __syncthreads();
  if (tid == 0){
    float s = 0.f;
    #pragma unroll
    for (int wq = 0; wq < 8; ++wq) s += wsum[wq];
    ws[W_PART + it*GG + g] = s;
  }
}

// ---------- K5: final loss reduction ----------
__global__ void k_final(float* __restrict__ out, const float* __restrict__ ws){
  int tid = threadIdx.x;
  double s = 0.0;
  for (int i = tid; i < NS*GG; i += 512) s += (double)ws[W_PART + i];
  __shared__ double rd[512];
  rd[tid] = s;
  __syncthreads();
  for (int st = 256; st > 0; st >>= 1){
    if (tid < st) rd[tid] += rd[tid + st];
    __syncthreads();
  }
  if (tid == 0) out[O_LOSS] = (float)(rd[0] * (0.5/6400.0));
}

extern "C" void kernel_launch(void* const* d_in, const int* in_sizes, int n_in,
                              void* d_out, int out_size, void* d_ws, size_t ws_size,
                              hipStream_t stream){
  const float* X   = (const float*)d_in[0];
  const float* Wz1 = (const float*)d_in[1];
  const float* bz1 = (const float*)d_in[2];
  const float* Wz2 = (const float*)d_in[3];
  const float* bz2 = (const float*)d_in[4];
  const float* Wa1 = (const float*)d_in[5];
  const float* ba1 = (const float*)d_in[6];
  const float* Wth = (const float*)d_in[7];
  const float* Wal = (const float*)d_in[8];
  const float* bal = (const float*)d_in[9];
  const float* Wd1 = (const float*)d_in[10];
  const float* bd1 = (const float*)d_in[11];
  const float* Wd2 = (const float*)d_in[12];
  const float* bd2 = (const float*)d_in[13];
  const int* seed  = (const int*)d_in[14];
  float* out = (float*)d_out;
  float* ws  = (float*)d_ws;

  hipLaunchKernelGGL(k_encode, dim3(32,64), dim3(256), 0, stream,
                     X, Wz1, bz1, Wz2, bz2, Wa1, ba1, out, ws);
  hipLaunchKernelGGL(k_alpha, dim3(64), dim3(256), 0, stream, Wal, bal, out, ws);
  hipLaunchKernelGGL(k_theta, dim3(8,32,64), dim3(256), 0, stream, Wth, out, ws);
  hipLaunchKernelGGL(k_loop, dim3(64,100), dim3(512), 0, stream,
                     Wd1, bd1, Wd2, bd2, X, seed, out, ws);
  hipLaunchKernelGGL(k_final, dim3(1), dim3(512), 0, stream, out, ws);
}